// Round 1
// baseline (2935.211 us; speedup 1.0000x reference)
//
#include <hip/hip_runtime.h>
#include <hip/hip_bf16.h>
#include <math.h>

// Problem constants: B=32, S=1024, D=1024, H=16, dh=64, T=8, E=8, HID=4096
// Outputs (fp32, concatenated): final (32*8*1024=262144), moe_loss (1), attn_weights (32*8*1024=262144)

// ---------------- workspace layout (float offsets) ----------------
static constexpr long OFF_Q       = 0;         // 8192   : q[t][d]
static constexpr long OFF_QW      = 8192;      // 131072 : qw[ht][d]  (scaled by 1/8)
static constexpr long OFF_QB      = 139264;    // 128    : qb[ht]     (scaled by 1/8)
static constexpr long OFF_PSUM    = 139392;    // 8
static constexpr long OFF_FCNT    = 139400;    // 8
static constexpr long OFF_CTX     = 139408;    // 262144 : ctx[bt][d]
static constexpr long OFF_ATTNOUT = 401552;    // 262144 : attn_out[bt][d]
static constexpr long OFF_Y       = 663696;    // 262144 : y[bt][d]
static constexpr long OFF_GATES   = 925840;    // 2048   : gates[bt][e]
static constexpr long OFF_SCORES  = 927888;    // 4194304: scores/attn [b][ht][s]
static constexpr long OFF_AX      = 5122192;   // 4194304: ax [h][b][t][d]
static constexpr long OFF_H       = 9316496;   // 8388608: h [e][n][hid]
static constexpr long OFF_EO      = 17705104;  // 2097152: eo [e][n][d]
// total = 19802256 floats = ~79.2 MB

// ---------------- q = probe @ wq^T + bq  (8 x 1024) ----------------
__global__ __launch_bounds__(256) void compute_q_k(const float* __restrict__ probe,
                                                   const float* __restrict__ in_w,
                                                   const float* __restrict__ in_b,
                                                   float* __restrict__ q) {
  int idx = blockIdx.x * 256 + threadIdx.x;   // t*1024 + d
  int t = idx >> 10, d = idx & 1023;
  float acc = in_b[d];
  const float* pr = probe + t * 1024;
  const float* wr = in_w + (long)d * 1024;    // wq row d
  for (int i = 0; i < 1024; ++i) acc += pr[i] * wr[i];
  q[idx] = acc;
}

// ---------------- qw[ht][d] = sum_j (q[t][h*64+j]/8) * wk[h*64+j][d]; qb[ht] ----------------
__global__ __launch_bounds__(256) void compute_qw_k(const float* __restrict__ q,
                                                    const float* __restrict__ in_w,
                                                    const float* __restrict__ in_b,
                                                    float* __restrict__ qw,
                                                    float* __restrict__ qb) {
  int ht = blockIdx.x;           // h*8 + t
  int h = ht >> 3, t = ht & 7;
  int tid = threadIdx.x;
  __shared__ float qh[64];
  if (tid < 64) qh[tid] = q[t * 1024 + h * 64 + tid] * 0.125f;
  __syncthreads();
  if (tid == 0) {
    float s = 0.f;
    for (int j = 0; j < 64; ++j) s += qh[j] * in_b[1024 + h * 64 + j];
    qb[ht] = s;
  }
  const float* wk = in_w + 1048576;  // D*D
  for (int d = tid; d < 1024; d += 256) {
    float a = 0.f;
    for (int j = 0; j < 64; ++j) a += qh[j] * wk[(long)(h * 64 + j) * 1024 + d];
    qw[(long)ht * 1024 + d] = a;
  }
}

// ---------------- generic fp32 tiled GEMM ----------------
// A: M x K row-major (lda=K). B: if B_NK, N x K row-major (ldb=K); else K x N (ldb=N).
// EPI: 0 plain; 1 scores-write (+bias[n], scatter [b][n][s]); 2 bias+gelu; 3 +bias[n]; 4 ax-write
template<int BM, int BN, int TM, int TN, bool B_NK, int EPI>
__global__ __launch_bounds__(256)
void gemm_f32(const float* __restrict__ A, const float* __restrict__ Bm,
              const float* __restrict__ bias, float* __restrict__ C,
              int M, int N, int K,
              long zA, long zB, long zBias, long zC, int ldc) {
  constexpr int BK = 16;
  const int z = blockIdx.z;
  A += zA * z;
  Bm += zB * z;
  bias += zBias * z;   // only dereferenced when EPI uses bias
  C += zC * z;
  const int m0 = blockIdx.y * BM;
  const int n0 = blockIdx.x * BN;
  __shared__ float As[BK][BM + 4];
  __shared__ float Bs[BK][BN + 4];
  const int tid = threadIdx.x;
  constexpr int NTX = BN / TN;
  const int tx = tid % NTX;
  const int ty = tid / NTX;
  float acc[TM][TN];
#pragma unroll
  for (int i = 0; i < TM; ++i)
#pragma unroll
    for (int j = 0; j < TN; ++j) acc[i][j] = 0.f;

  for (int k0 = 0; k0 < K; k0 += BK) {
    for (int i = tid; i < BK * BM; i += 256) {
      int k = i & (BK - 1);
      int m = i >> 4;
      As[k][m] = A[(long)(m0 + m) * K + k0 + k];
    }
    if constexpr (B_NK) {
      for (int i = tid; i < BK * BN; i += 256) {
        int k = i & (BK - 1);
        int n = i >> 4;
        Bs[k][n] = Bm[(long)(n0 + n) * K + k0 + k];
      }
    } else {
      for (int i = tid; i < BK * BN; i += 256) {
        int n = i % BN;
        int k = i / BN;
        Bs[k][n] = Bm[(long)(k0 + k) * N + n0 + n];
      }
    }
    __syncthreads();
#pragma unroll
    for (int k = 0; k < BK; ++k) {
      float a[TM], b[TN];
#pragma unroll
      for (int i = 0; i < TM; i += 4)
        *(float4*)&a[i] = *(const float4*)&As[k][ty * TM + i];
#pragma unroll
      for (int j = 0; j < TN; j += 4)
        *(float4*)&b[j] = *(const float4*)&Bs[k][tx * TN + j];
#pragma unroll
      for (int i = 0; i < TM; ++i)
#pragma unroll
        for (int j = 0; j < TN; ++j) acc[i][j] = fmaf(a[i], b[j], acc[i][j]);
    }
    __syncthreads();
  }

#pragma unroll
  for (int i = 0; i < TM; ++i) {
    int m = m0 + ty * TM + i;
#pragma unroll
    for (int j = 0; j < TN; ++j) {
      int n = n0 + tx * TN + j;
      float v = acc[i][j];
      if constexpr (EPI == 0) {
        C[(long)m * ldc + n] = v;
      } else if constexpr (EPI == 1) {
        // scores: m = b*1024 + s ; write scores[b][n][s] = v + qb[n]
        C[(long)(m >> 10) * 131072 + (long)n * 1024 + (m & 1023)] = v + bias[n];
      } else if constexpr (EPI == 2) {
        v += bias[n];
        C[(long)m * ldc + n] = 0.5f * v * (1.0f + erff(v * 0.70710678118654752f));
      } else if constexpr (EPI == 3) {
        C[(long)m * ldc + n] = v + bias[n];
      } else {
        // ax: m = h*8 + t ; C already offset by b*8192 ; write [h][b][t][d]
        C[(long)(m >> 3) * 262144 + (long)(m & 7) * 1024 + n] = v;
      }
    }
  }
}

// ---------------- softmax over s (in place), rows = b*128 + ht ----------------
__global__ __launch_bounds__(256) void softmax_k(float* __restrict__ scores) {
  long row = blockIdx.x;
  float* p = scores + row * 1024;
  int tid = threadIdx.x;
  int wid = tid >> 6, lane = tid & 63;
  float v[4];
  float mx = -1e30f;
#pragma unroll
  for (int i = 0; i < 4; ++i) { v[i] = p[tid + i * 256]; mx = fmaxf(mx, v[i]); }
  for (int o = 32; o; o >>= 1) mx = fmaxf(mx, __shfl_xor(mx, o));
  __shared__ float sm[4];
  __shared__ float ss[4];
  if (!lane) sm[wid] = mx;
  __syncthreads();
  mx = fmaxf(fmaxf(sm[0], sm[1]), fmaxf(sm[2], sm[3]));
  float s = 0.f;
#pragma unroll
  for (int i = 0; i < 4; ++i) { v[i] = expf(v[i] - mx); s += v[i]; }
  for (int o = 32; o; o >>= 1) s += __shfl_xor(s, o);
  if (!lane) ss[wid] = s;
  __syncthreads();
  s = ss[0] + ss[1] + ss[2] + ss[3];
  float inv = 1.0f / s;
#pragma unroll
  for (int i = 0; i < 4; ++i) p[tid + i * 256] = v[i] * inv;
}

// ---------------- attn_weights[b][t][s] = mean_h attn[b][h*8+t][s] ----------------
__global__ __launch_bounds__(256) void attnw_k(const float* __restrict__ attn,
                                               float* __restrict__ outw) {
  int idx = blockIdx.x * 256 + threadIdx.x;   // b*8192 + t*1024 + s
  int b = idx >> 13;
  int r = idx & 8191;
  int t = r >> 10, s = r & 1023;
  const float* p = attn + (long)b * 131072 + (long)t * 1024 + s;
  float acc = 0.f;
#pragma unroll
  for (int h = 0; h < 16; ++h) acc += p[(long)h * 8192];
  outw[idx] = acc * (1.0f / 16.0f);
}

// ---------------- layernorm + gate softmax + top2 (one block per token row) ----------------
__global__ __launch_bounds__(256) void ln_gate_k(const float* __restrict__ attn_out,
                                                 const float* __restrict__ gamma,
                                                 const float* __restrict__ beta,
                                                 const float* __restrict__ gate_w,
                                                 float* __restrict__ y,
                                                 float* __restrict__ gates,
                                                 float* __restrict__ Psum,
                                                 float* __restrict__ fcnt) {
  int row = blockIdx.x;        // n = b*8 + t
  int t = row & 7;
  int tid = threadIdx.x;
  int wid = tid >> 6, lane = tid & 63;
  const float* xr = attn_out + (long)row * 1024;
  float vals[4];
  float s = 0.f, sq = 0.f;
#pragma unroll
  for (int i = 0; i < 4; ++i) {
    float v = xr[tid + i * 256];
    vals[i] = v;
    s += v;
    sq += v * v;
  }
  for (int o = 32; o; o >>= 1) { s += __shfl_xor(s, o); sq += __shfl_xor(sq, o); }
  __shared__ float rs[4], rss[4];
  if (!lane) { rs[wid] = s; rss[wid] = sq; }
  __syncthreads();
  s = rs[0] + rs[1] + rs[2] + rs[3];
  sq = rss[0] + rss[1] + rss[2] + rss[3];
  float mu = s * (1.0f / 1024.0f);
  float var = sq * (1.0f / 1024.0f) - mu * mu;
  float rstd = rsqrtf(var + 1e-5f);
  __shared__ float yrow[1024];
#pragma unroll
  for (int i = 0; i < 4; ++i) {
    int d = tid + i * 256;
    float yv = (vals[i] - mu) * rstd * gamma[d] + beta[d];
    y[(long)row * 1024 + d] = yv;
    yrow[d] = yv;
  }
  __syncthreads();
  // logits[e] = sum_d yrow[d] * gate_w[t][d][e]
  int e = tid & 7;
  int g = tid >> 3;  // 32 groups
  float acc = 0.f;
  const float* gw = gate_w + (long)t * 8192;
  for (int d = g; d < 1024; d += 32) acc += yrow[d] * gw[d * 8 + e];
  __shared__ float part[256];
  __shared__ float lsh[8];
  part[tid] = acc;
  __syncthreads();
  if (tid < 8) {
    float l = 0.f;
    for (int gg = 0; gg < 32; ++gg) l += part[gg * 8 + tid];
    lsh[tid] = l;
  }
  __syncthreads();
  if (tid == 0) {
    float p[8];
    float mx = -1e30f;
    for (int k = 0; k < 8; ++k) mx = fmaxf(mx, lsh[k]);
    float sum = 0.f;
    for (int k = 0; k < 8; ++k) { p[k] = expf(lsh[k] - mx); sum += p[k]; }
    float inv = 1.0f / sum;
    for (int k = 0; k < 8; ++k) p[k] *= inv;
    int i0 = 0;
    for (int k = 1; k < 8; ++k) if (p[k] > p[i0]) i0 = k;
    int i1 = -1;
    for (int k = 0; k < 8; ++k) if (k != i0 && (i1 < 0 || p[k] > p[i1])) i1 = k;
    float tot = p[i0] + p[i1];
    for (int k = 0; k < 8; ++k)
      gates[(long)row * 8 + k] = (k == i0) ? p[i0] / tot : (k == i1) ? p[i1] / tot : 0.f;
    for (int k = 0; k < 8; ++k) atomicAdd(&Psum[k], p[k]);
    atomicAdd(&fcnt[i0], 1.0f);
    atomicAdd(&fcnt[i1], 1.0f);
  }
}

// ---------------- final = attn_out + sum_e gates[n][e] * eo[e][n][:] ----------------
__global__ __launch_bounds__(256) void combine_k(const float* __restrict__ attn_out,
                                                 const float* __restrict__ eo,
                                                 const float* __restrict__ gates,
                                                 float* __restrict__ outp) {
  int idx = blockIdx.x * 256 + threadIdx.x;  // n*1024 + d
  int n = idx >> 10;
  float v = attn_out[idx];
  const float* g = gates + (long)n * 8;
#pragma unroll
  for (int e = 0; e < 8; ++e) {
    float ge = g[e];
    if (ge != 0.f) v += ge * eo[(long)e * 262144 + idx];
  }
  outp[idx] = v;
}

__global__ void loss_k(const float* __restrict__ Psum, const float* __restrict__ fcnt,
                       float* __restrict__ out) {
  if (threadIdx.x == 0) {
    float l = 0.f;
    for (int e = 0; e < 8; ++e) l += (fcnt[e] * (1.0f / 256.0f)) * (Psum[e] * (1.0f / 256.0f));
    out[0] = 8.0f * l;
  }
}

extern "C" void kernel_launch(void* const* d_in, const int* in_sizes, int n_in,
                              void* d_out, int out_size, void* d_ws, size_t ws_size,
                              hipStream_t stream) {
  const float* x      = (const float*)d_in[0];
  const float* probe  = (const float*)d_in[1];
  const float* in_w   = (const float*)d_in[2];
  const float* in_b   = (const float*)d_in[3];
  const float* out_w  = (const float*)d_in[4];
  const float* out_b  = (const float*)d_in[5];
  const float* gamma  = (const float*)d_in[6];
  const float* beta   = (const float*)d_in[7];
  const float* gate_w = (const float*)d_in[8];
  const float* w1     = (const float*)d_in[9];
  const float* b1     = (const float*)d_in[10];
  const float* w2     = (const float*)d_in[11];
  const float* b2     = (const float*)d_in[12];

  float* ws = (float*)d_ws;
  float* q        = ws + OFF_Q;
  float* qw       = ws + OFF_QW;
  float* qb       = ws + OFF_QB;
  float* Psum     = ws + OFF_PSUM;
  float* fcnt     = ws + OFF_FCNT;
  float* ctx      = ws + OFF_CTX;
  float* attn_out = ws + OFF_ATTNOUT;
  float* y        = ws + OFF_Y;
  float* gates    = ws + OFF_GATES;
  float* scores   = ws + OFF_SCORES;
  float* ax       = ws + OFF_AX;
  float* h_act    = ws + OFF_H;
  float* eo       = ws + OFF_EO;

  float* out_final = (float*)d_out;            // 262144
  float* out_loss  = out_final + 262144;       // 1
  float* out_attnw = out_loss + 1;             // 262144

  // q (8x1024), then qw (128x1024) + qb (128)
  compute_q_k<<<32, 256, 0, stream>>>(probe, in_w, in_b, q);
  compute_qw_k<<<128, 256, 0, stream>>>(q, in_w, in_b, qw, qb);

  // scores[b][ht][s] = x @ qw^T + qb   (M=32768, N=128, K=1024)
  gemm_f32<128, 128, 8, 8, true, 1><<<dim3(1, 256, 1), 256, 0, stream>>>(
      x, qw, qb, scores, 32768, 128, 1024, 0, 0, 0, 0, 1024);

  // softmax over s, in place
  softmax_k<<<4096, 256, 0, stream>>>(scores);

  // attn_weights output
  attnw_k<<<1024, 256, 0, stream>>>(scores, out_attnw);

  // ax[h][b][t][d] = attn[b] @ x[b]   (per b: M=128, N=1024, K=1024)
  gemm_f32<128, 128, 8, 8, false, 4><<<dim3(8, 1, 32), 256, 0, stream>>>(
      scores, x, (const float*)nullptr, ax, 128, 1024, 1024,
      131072L, 1048576L, 0L, 8192L, 1024);

  // ctx[bt][h*64+j] = ax[h] @ wv_h^T + bv_h   (per h: M=256, N=64, K=1024)
  gemm_f32<64, 64, 4, 4, true, 3><<<dim3(1, 4, 16), 256, 0, stream>>>(
      ax, in_w + 2097152, in_b + 2048, ctx, 256, 64, 1024,
      262144L, 65536L, 64L, 64L, 1024);

  // attn_out = ctx @ out_w^T + out_b   (M=256, N=1024, K=1024)
  gemm_f32<64, 128, 4, 8, true, 3><<<dim3(8, 4, 1), 256, 0, stream>>>(
      ctx, out_w, out_b, attn_out, 256, 1024, 1024, 0, 0, 0, 0, 1024);

  // zero loss accumulators (Psum 8 + fcnt 8, contiguous)
  hipMemsetAsync(ws + OFF_PSUM, 0, 16 * sizeof(float), stream);

  // layernorm + gate + top2
  ln_gate_k<<<256, 256, 0, stream>>>(attn_out, gamma, beta, gate_w, y, gates, Psum, fcnt);

  // h[e] = gelu(y @ w1[e] + b1[e])   (per e: M=256, N=4096, K=1024)
  gemm_f32<128, 128, 8, 8, false, 2><<<dim3(32, 2, 8), 256, 0, stream>>>(
      y, w1, b1, h_act, 256, 4096, 1024, 0L, 4194304L, 4096L, 1048576L, 4096);

  // eo[e] = h[e] @ w2[e] + b2[e]   (per e: M=256, N=1024, K=4096)
  gemm_f32<64, 128, 4, 8, false, 3><<<dim3(8, 4, 8), 256, 0, stream>>>(
      h_act, w2, b2, eo, 256, 1024, 4096, 1048576L, 4194304L, 1024L, 262144L, 1024);

  // final = attn_out + gated expert mix
  combine_k<<<1024, 256, 0, stream>>>(attn_out, eo, gates, out_final);

  // moe aux loss
  loss_k<<<1, 64, 0, stream>>>(Psum, fcnt, out_loss);
}

// Round 3
// 901.953 us; speedup vs baseline: 3.2543x; 3.2543x over previous
//
#include <hip/hip_runtime.h>
#include <hip/hip_bf16.h>
#include <math.h>

// B=32, S=1024, D=1024, H=16, dh=64, T=8, E=8, HID=4096
// Outputs fp32 concat: final(262144), moe_loss(1), attn_weights(262144)

using bf16x8  = __attribute__((ext_vector_type(8))) short;
using f32x4   = __attribute__((ext_vector_type(4))) float;
using short4v = __attribute__((ext_vector_type(4))) short;

__device__ inline short f2bf(float f) {
  unsigned u = __builtin_bit_cast(unsigned, f);
  u = (u + 0x7fffu + ((u >> 16) & 1u)) >> 16;
  return (short)u;
}
__device__ inline float bf2f(short h) {
  unsigned u = ((unsigned)(unsigned short)h) << 16;
  return __builtin_bit_cast(float, u);
}

// ---------------- workspace layout (float offsets) ----------------
static constexpr long OFF_Q       = 0;          // 8192
static constexpr long OFF_QW      = 8192;       // 131072
static constexpr long OFF_QB      = 139264;     // 128
static constexpr long OFF_PSUM    = 139392;     // 8
static constexpr long OFF_FCNT    = 139400;     // 8
static constexpr long OFF_ATTNOUT = 139408;     // 262144 fp32
static constexpr long OFF_GATES   = 401552;     // 2048
static constexpr long OFF_CTX     = 403600;     // 262144 fp32
static constexpr long OFF_SCORES  = 665744;     // 4194304 fp32 [b][ht][s]
static constexpr long OFF_AX      = 4860048;    // 4194304 fp32 [h][b][t][d]
static constexpr long OFF_EO      = 9054352;    // 2097152 fp32 [e][n][d]
static constexpr long OFF_YB      = 11151504;   // 131072 f = 262144 bf16
static constexpr long OFF_HB      = 11282576;   // 4194304 f = 8388608 bf16 [e][n][hid]
// total 15476880 floats ~ 61.9 MB

// ---------------- q: one wave per output element ----------------
__global__ __launch_bounds__(256) void compute_q_k(const float* __restrict__ probe,
                                                   const float* __restrict__ in_w,
                                                   const float* __restrict__ in_b,
                                                   float* __restrict__ q) {
  int wid = threadIdx.x >> 6, lane = threadIdx.x & 63;
  int idx = blockIdx.x * 4 + wid;   // t*1024 + d
  int t = idx >> 10, d = idx & 1023;
  const float* pr = probe + (long)t * 1024;
  const float* wr = in_w + (long)d * 1024;
  float s = 0.f;
  for (int k = lane * 4; k < 1024; k += 256) {
    float4 a = *(const float4*)&pr[k];
    float4 b = *(const float4*)&wr[k];
    s += a.x * b.x + a.y * b.y + a.z * b.z + a.w * b.w;
  }
  for (int o = 32; o; o >>= 1) s += __shfl_xor(s, o);
  if (!lane) q[idx] = s + in_b[d];
}

// ---------------- qw[ht][d] = sum_j (q[t][h*64+j]/8) * wk[h*64+j][d]; qb[ht] ----------------
__global__ __launch_bounds__(256) void compute_qw_k(const float* __restrict__ q,
                                                    const float* __restrict__ in_w,
                                                    const float* __restrict__ in_b,
                                                    float* __restrict__ qw,
                                                    float* __restrict__ qb) {
  int ht = blockIdx.x;           // h*8 + t
  int h = ht >> 3, t = ht & 7;
  int tid = threadIdx.x;
  __shared__ float qh[64];
  if (tid < 64) qh[tid] = q[t * 1024 + h * 64 + tid] * 0.125f;
  __syncthreads();
  if (tid == 0) {
    float s = 0.f;
    for (int j = 0; j < 64; ++j) s += qh[j] * in_b[1024 + h * 64 + j];
    qb[ht] = s;
  }
  const float* wk = in_w + 1048576;
  for (int d = tid; d < 1024; d += 256) {
    float a = 0.f;
    for (int j = 0; j < 64; ++j) a += qh[j] * wk[(long)(h * 64 + j) * 1024 + d];
    qw[(long)ht * 1024 + d] = a;
  }
}

// ---------------- split-bf16 MFMA GEMM (fp32-grade accuracy) ----------------
// A: M x K fp32 row-major. B: fp32; B_NK: N x K (C = A B^T), else K x N.
// Each fp32 v is split hi=bf16(v), lo=bf16(v-hi); acc += ah*bh + ah*bl + al*bh.
// EPI: 0 fp32 +bias (ldc); 1 scores scatter +bias; 4 ax fp32 scatter
template<int BM, int BN, int WM, int WN, bool B_NK, int EPI>
__global__ __launch_bounds__(WM * WN * 64)
void gemm_split(const float* __restrict__ Ap, const float* __restrict__ Bp,
                const float* __restrict__ biasp, float* __restrict__ Cp,
                int M, int N, int K, long zA, long zB, long zBias, long zC, int ldc) {
  constexpr int BK = 32, NT = WM * WN * 64, PK = 40;
  const int z = blockIdx.z;
  const float* A = Ap + zA * z;
  const float* B = Bp + zB * z;
  const float* bias = biasp + zBias * z;
  float* C = Cp + zC * z;
  const int tid = threadIdx.x;
  const int m0 = blockIdx.y * BM, n0 = blockIdx.x * BN;
  __shared__ short Ah[BM][PK], Al[BM][PK];
  __shared__ short Bh[BN][PK], Bl[BN][PK];

  f32x4 acc[4][4];
#pragma unroll
  for (int i = 0; i < 4; ++i)
#pragma unroll
    for (int j = 0; j < 4; ++j)
#pragma unroll
      for (int qq = 0; qq < 4; ++qq) acc[i][j][qq] = 0.f;

  const int wid = tid >> 6, lane = tid & 63;
  const int wm = wid % WM, wn = wid / WM;
  const int r = lane & 15, kg = (lane >> 4) * 8;

  for (int k0 = 0; k0 < K; k0 += BK) {
    // ---- stage A (fp32 -> hi/lo) ----
    {
      constexpr int ITER = BM * BK / (NT * 4);
#pragma unroll
      for (int i = 0; i < ITER; ++i) {
        int f = tid + i * NT;
        int m = f >> 3, k4 = (f & 7) * 4;
        float4 v = *(const float4*)&A[(long)(m0 + m) * K + k0 + k4];
        short4v h, l;
        h.x = f2bf(v.x); l.x = f2bf(v.x - bf2f(h.x));
        h.y = f2bf(v.y); l.y = f2bf(v.y - bf2f(h.y));
        h.z = f2bf(v.z); l.z = f2bf(v.z - bf2f(h.z));
        h.w = f2bf(v.w); l.w = f2bf(v.w - bf2f(h.w));
        *(short4v*)&Ah[m][k4] = h;
        *(short4v*)&Al[m][k4] = l;
      }
    }
    // ---- stage B ----
    if constexpr (B_NK) {
      constexpr int ITER = BN * BK / (NT * 4);
#pragma unroll
      for (int i = 0; i < ITER; ++i) {
        int f = tid + i * NT;
        int n = f >> 3, k4 = (f & 7) * 4;
        float4 v = *(const float4*)&B[(long)(n0 + n) * K + k0 + k4];
        short4v h, l;
        h.x = f2bf(v.x); l.x = f2bf(v.x - bf2f(h.x));
        h.y = f2bf(v.y); l.y = f2bf(v.y - bf2f(h.y));
        h.z = f2bf(v.z); l.z = f2bf(v.z - bf2f(h.z));
        h.w = f2bf(v.w); l.w = f2bf(v.w - bf2f(h.w));
        *(short4v*)&Bh[n][k4] = h;
        *(short4v*)&Bl[n][k4] = l;
      }
    } else {
      constexpr int ITER = BN * BK / (NT * 4);
      constexpr int RF4 = BN / 4;
#pragma unroll
      for (int i = 0; i < ITER; ++i) {
        int f = tid + i * NT;
        int k = f / RF4, n4 = (f % RF4) * 4;
        float4 v = *(const float4*)&B[(long)(k0 + k) * N + n0 + n4];
        short hh;
        hh = f2bf(v.x); Bh[n4 + 0][k] = hh; Bl[n4 + 0][k] = f2bf(v.x - bf2f(hh));
        hh = f2bf(v.y); Bh[n4 + 1][k] = hh; Bl[n4 + 1][k] = f2bf(v.y - bf2f(hh));
        hh = f2bf(v.z); Bh[n4 + 2][k] = hh; Bl[n4 + 2][k] = f2bf(v.z - bf2f(hh));
        hh = f2bf(v.w); Bh[n4 + 3][k] = hh; Bl[n4 + 3][k] = f2bf(v.w - bf2f(hh));
      }
    }
    __syncthreads();
    // ---- compute: 3 MFMAs per tile ----
    bf16x8 ah[4], al[4], bh[4], bl[4];
#pragma unroll
    for (int i = 0; i < 4; ++i) {
      ah[i] = *(const bf16x8*)&Ah[wm * 64 + i * 16 + r][kg];
      al[i] = *(const bf16x8*)&Al[wm * 64 + i * 16 + r][kg];
    }
#pragma unroll
    for (int j = 0; j < 4; ++j) {
      bh[j] = *(const bf16x8*)&Bh[wn * 64 + j * 16 + r][kg];
      bl[j] = *(const bf16x8*)&Bl[wn * 64 + j * 16 + r][kg];
    }
#pragma unroll
    for (int i = 0; i < 4; ++i)
#pragma unroll
      for (int j = 0; j < 4; ++j) {
        acc[i][j] = __builtin_amdgcn_mfma_f32_16x16x32_bf16(ah[i], bh[j], acc[i][j], 0, 0, 0);
        acc[i][j] = __builtin_amdgcn_mfma_f32_16x16x32_bf16(ah[i], bl[j], acc[i][j], 0, 0, 0);
        acc[i][j] = __builtin_amdgcn_mfma_f32_16x16x32_bf16(al[i], bh[j], acc[i][j], 0, 0, 0);
      }
    __syncthreads();
  }

  // ---- epilogue ----
  const int q4 = (lane >> 4) * 4;
#pragma unroll
  for (int i = 0; i < 4; ++i) {
    int gmb = m0 + wm * 64 + i * 16 + q4;
#pragma unroll
    for (int j = 0; j < 4; ++j) {
      int gn = n0 + wn * 64 + j * 16 + r;
#pragma unroll
      for (int qq = 0; qq < 4; ++qq) {
        float v = acc[i][j][qq];
        int m = gmb + qq;
        if constexpr (EPI == 0) {
          C[(long)m * ldc + gn] = v + bias[gn];
        } else if constexpr (EPI == 1) {
          // m = b*1024+s ; write scores[b][ht=gn][s]
          Cp[(long)(m >> 10) * 131072 + (long)gn * 1024 + (m & 1023)] = v + bias[gn];
        } else {
          // EPI==4: m = h*8+t ; C offset by z*8192 ; write ax[h][b][t][d]
          C[(long)(m >> 3) * 262144 + (long)(m & 7) * 1024 + gn] = v;
        }
      }
    }
  }
}

// ---------------- plain bf16 MFMA GEMM (MoE experts) ----------------
// A: M x K bf16 row-major. B: fp32 K x N (transpose-staged).
// EPI: 0 fp32 +bias; 2 gelu->bf16 +bias
template<int BM, int BN, int WM, int WN, int EPI>
__global__ __launch_bounds__(WM * WN * 64)
void gemm_bf16(const short* __restrict__ Ap, const float* __restrict__ Bp,
               const float* __restrict__ biasp, void* __restrict__ Cp,
               int M, int N, int K, long zA, long zB, long zBias, long zC, int ldc) {
  constexpr int BK = 32, NT = WM * WN * 64, PK = 40;
  const int z = blockIdx.z;
  const short* A = Ap + zA * z;
  const float* B = Bp + zB * z;
  const float* bias = biasp + zBias * z;
  const int tid = threadIdx.x;
  const int m0 = blockIdx.y * BM, n0 = blockIdx.x * BN;
  __shared__ short As[BM][PK];
  __shared__ short Bs[BN][PK];

  f32x4 acc[4][4];
#pragma unroll
  for (int i = 0; i < 4; ++i)
#pragma unroll
    for (int j = 0; j < 4; ++j)
#pragma unroll
      for (int qq = 0; qq < 4; ++qq) acc[i][j][qq] = 0.f;

  const int wid = tid >> 6, lane = tid & 63;
  const int wm = wid % WM, wn = wid / WM;
  const int r = lane & 15, kg = (lane >> 4) * 8;

  for (int k0 = 0; k0 < K; k0 += BK) {
    {
      constexpr int ITER = BM * BK / (NT * 8);
#pragma unroll
      for (int i = 0; i < ITER; ++i) {
        int f = tid + i * NT;
        int m = f >> 2, k8 = (f & 3) * 8;
        bf16x8 v = *(const bf16x8*)&A[(long)(m0 + m) * K + k0 + k8];
        *(bf16x8*)&As[m][k8] = v;
      }
    }
    {
      constexpr int ITER = BN * BK / (NT * 4);
      constexpr int RF4 = BN / 4;
#pragma unroll
      for (int i = 0; i < ITER; ++i) {
        int f = tid + i * NT;
        int k = f / RF4, n4 = (f % RF4) * 4;
        float4 v = *(const float4*)&B[(long)(k0 + k) * N + n0 + n4];
        Bs[n4 + 0][k] = f2bf(v.x);
        Bs[n4 + 1][k] = f2bf(v.y);
        Bs[n4 + 2][k] = f2bf(v.z);
        Bs[n4 + 3][k] = f2bf(v.w);
      }
    }
    __syncthreads();
    bf16x8 af[4], bfr[4];
#pragma unroll
    for (int i = 0; i < 4; ++i) af[i] = *(const bf16x8*)&As[wm * 64 + i * 16 + r][kg];
#pragma unroll
    for (int j = 0; j < 4; ++j) bfr[j] = *(const bf16x8*)&Bs[wn * 64 + j * 16 + r][kg];
#pragma unroll
    for (int i = 0; i < 4; ++i)
#pragma unroll
      for (int j = 0; j < 4; ++j)
        acc[i][j] = __builtin_amdgcn_mfma_f32_16x16x32_bf16(af[i], bfr[j], acc[i][j], 0, 0, 0);
    __syncthreads();
  }

  const int q4 = (lane >> 4) * 4;
#pragma unroll
  for (int i = 0; i < 4; ++i) {
    int gmb = m0 + wm * 64 + i * 16 + q4;
#pragma unroll
    for (int j = 0; j < 4; ++j) {
      int gn = n0 + wn * 64 + j * 16 + r;
#pragma unroll
      for (int qq = 0; qq < 4; ++qq) {
        float v = acc[i][j][qq] + bias[gn];
        int m = gmb + qq;
        if constexpr (EPI == 0) {
          ((float*)Cp + zC * z)[(long)m * ldc + gn] = v;
        } else {
          float u = 0.5f * v * (1.0f + erff(v * 0.70710678118654752f));
          ((short*)Cp + zC * z)[(long)m * ldc + gn] = f2bf(u);
        }
      }
    }
  }
}

// ---------------- softmax over s (in place) ----------------
__global__ __launch_bounds__(256) void softmax_k(float* __restrict__ scores) {
  long row = blockIdx.x;
  float* p = scores + row * 1024;
  int tid = threadIdx.x;
  int wid = tid >> 6, lane = tid & 63;
  float v[4];
  float mx = -1e30f;
#pragma unroll
  for (int i = 0; i < 4; ++i) { v[i] = p[tid + i * 256]; mx = fmaxf(mx, v[i]); }
  for (int o = 32; o; o >>= 1) mx = fmaxf(mx, __shfl_xor(mx, o));
  __shared__ float sm[4];
  __shared__ float ss[4];
  if (!lane) sm[wid] = mx;
  __syncthreads();
  mx = fmaxf(fmaxf(sm[0], sm[1]), fmaxf(sm[2], sm[3]));
  float s = 0.f;
#pragma unroll
  for (int i = 0; i < 4; ++i) { v[i] = expf(v[i] - mx); s += v[i]; }
  for (int o = 32; o; o >>= 1) s += __shfl_xor(s, o);
  if (!lane) ss[wid] = s;
  __syncthreads();
  s = ss[0] + ss[1] + ss[2] + ss[3];
  float inv = 1.0f / s;
#pragma unroll
  for (int i = 0; i < 4; ++i) p[tid + i * 256] = v[i] * inv;
}

// ---------------- attn_weights[b][t][s] = mean_h attn ----------------
__global__ __launch_bounds__(256) void attnw_k(const float* __restrict__ attn,
                                               float* __restrict__ outw) {
  int idx = blockIdx.x * 256 + threadIdx.x;
  int b = idx >> 13;
  int r = idx & 8191;
  int t = r >> 10, s = r & 1023;
  const float* p = attn + (long)b * 131072 + (long)t * 1024 + s;
  float acc = 0.f;
#pragma unroll
  for (int h = 0; h < 16; ++h) acc += p[(long)h * 8192];
  outw[idx] = acc * (1.0f / 16.0f);
}

// ---------------- layernorm + gate softmax + top2 ----------------
__global__ __launch_bounds__(256) void ln_gate_k(const float* __restrict__ attn_out,
                                                 const float* __restrict__ gamma,
                                                 const float* __restrict__ beta,
                                                 const float* __restrict__ gate_w,
                                                 short* __restrict__ yb,
                                                 float* __restrict__ gates,
                                                 float* __restrict__ Psum,
                                                 float* __restrict__ fcnt) {
  int row = blockIdx.x;        // n = b*8 + t
  int t = row & 7;
  int tid = threadIdx.x;
  int wid = tid >> 6, lane = tid & 63;
  const float* xr = attn_out + (long)row * 1024;
  float vals[4];
  float s = 0.f, sq = 0.f;
#pragma unroll
  for (int i = 0; i < 4; ++i) {
    float v = xr[tid + i * 256];
    vals[i] = v;
    s += v;
    sq += v * v;
  }
  for (int o = 32; o; o >>= 1) { s += __shfl_xor(s, o); sq += __shfl_xor(sq, o); }
  __shared__ float rs[4], rss[4];
  if (!lane) { rs[wid] = s; rss[wid] = sq; }
  __syncthreads();
  s = rs[0] + rs[1] + rs[2] + rs[3];
  sq = rss[0] + rss[1] + rss[2] + rss[3];
  float mu = s * (1.0f / 1024.0f);
  float var = sq * (1.0f / 1024.0f) - mu * mu;
  float rstd = rsqrtf(var + 1e-5f);
  __shared__ float yrow[1024];
#pragma unroll
  for (int i = 0; i < 4; ++i) {
    int d = tid + i * 256;
    float yv = (vals[i] - mu) * rstd * gamma[d] + beta[d];
    yb[(long)row * 1024 + d] = f2bf(yv);
    yrow[d] = yv;
  }
  __syncthreads();
  int e = tid & 7;
  int g = tid >> 3;
  float acc = 0.f;
  const float* gw = gate_w + (long)t * 8192;
  for (int d = g; d < 1024; d += 32) acc += yrow[d] * gw[d * 8 + e];
  __shared__ float part[256];
  __shared__ float lsh[8];
  part[tid] = acc;
  __syncthreads();
  if (tid < 8) {
    float l = 0.f;
    for (int gg = 0; gg < 32; ++gg) l += part[gg * 8 + tid];
    lsh[tid] = l;
  }
  __syncthreads();
  if (tid == 0) {
    float p[8];
    float mx = -1e30f;
    for (int k = 0; k < 8; ++k) mx = fmaxf(mx, lsh[k]);
    float sum = 0.f;
    for (int k = 0; k < 8; ++k) { p[k] = expf(lsh[k] - mx); sum += p[k]; }
    float inv = 1.0f / sum;
    for (int k = 0; k < 8; ++k) p[k] *= inv;
    int i0 = 0;
    for (int k = 1; k < 8; ++k) if (p[k] > p[i0]) i0 = k;
    int i1 = -1;
    for (int k = 0; k < 8; ++k) if (k != i0 && (i1 < 0 || p[k] > p[i1])) i1 = k;
    float tot = p[i0] + p[i1];
    for (int k = 0; k < 8; ++k)
      gates[(long)row * 8 + k] = (k == i0) ? p[i0] / tot : (k == i1) ? p[i1] / tot : 0.f;
    for (int k = 0; k < 8; ++k) atomicAdd(&Psum[k], p[k]);
    atomicAdd(&fcnt[i0], 1.0f);
    atomicAdd(&fcnt[i1], 1.0f);
  }
}

// ---------------- final = attn_out + sum_e gates[n][e] * eo[e][n][:] ----------------
__global__ __launch_bounds__(256) void combine_k(const float* __restrict__ attn_out,
                                                 const float* __restrict__ eo,
                                                 const float* __restrict__ gates,
                                                 float* __restrict__ outp) {
  int idx = blockIdx.x * 256 + threadIdx.x;
  int n = idx >> 10;
  float v = attn_out[idx];
  const float* g = gates + (long)n * 8;
#pragma unroll
  for (int e = 0; e < 8; ++e) {
    float ge = g[e];
    if (ge != 0.f) v += ge * eo[(long)e * 262144 + idx];
  }
  outp[idx] = v;
}

__global__ void loss_k(const float* __restrict__ Psum, const float* __restrict__ fcnt,
                       float* __restrict__ out) {
  if (threadIdx.x == 0) {
    float l = 0.f;
    for (int e = 0; e < 8; ++e) l += (fcnt[e] * (1.0f / 256.0f)) * (Psum[e] * (1.0f / 256.0f));
    out[0] = 8.0f * l;
  }
}

extern "C" void kernel_launch(void* const* d_in, const int* in_sizes, int n_in,
                              void* d_out, int out_size, void* d_ws, size_t ws_size,
                              hipStream_t stream) {
  const float* x      = (const float*)d_in[0];
  const float* probe  = (const float*)d_in[1];
  const float* in_w   = (const float*)d_in[2];
  const float* in_b   = (const float*)d_in[3];
  const float* out_w  = (const float*)d_in[4];
  const float* out_b  = (const float*)d_in[5];
  const float* gamma  = (const float*)d_in[6];
  const float* beta   = (const float*)d_in[7];
  const float* gate_w = (const float*)d_in[8];
  const float* w1     = (const float*)d_in[9];
  const float* b1     = (const float*)d_in[10];
  const float* w2     = (const float*)d_in[11];
  const float* b2     = (const float*)d_in[12];

  float* ws = (float*)d_ws;
  float* q        = ws + OFF_Q;
  float* qw       = ws + OFF_QW;
  float* qb       = ws + OFF_QB;
  float* Psum     = ws + OFF_PSUM;
  float* fcnt     = ws + OFF_FCNT;
  float* attn_out = ws + OFF_ATTNOUT;
  float* gates    = ws + OFF_GATES;
  float* ctx      = ws + OFF_CTX;
  float* scores   = ws + OFF_SCORES;
  float* ax       = ws + OFF_AX;
  float* eo       = ws + OFF_EO;
  short* yb       = (short*)(ws + OFF_YB);
  short* hb       = (short*)(ws + OFF_HB);

  float* out_final = (float*)d_out;
  float* out_loss  = out_final + 262144;
  float* out_attnw = out_loss + 1;

  compute_q_k<<<2048, 256, 0, stream>>>(probe, in_w, in_b, q);
  compute_qw_k<<<128, 256, 0, stream>>>(q, in_w, in_b, qw, qb);

  // scores[b][ht][s] = x @ qw^T + qb   (M=32768, N=128, K=1024) — split precision
  gemm_split<128, 128, 2, 2, true, 1><<<dim3(1, 256, 1), 256, 0, stream>>>(
      x, qw, qb, scores, 32768, 128, 1024, 0, 0, 0, 0, 1024);

  softmax_k<<<4096, 256, 0, stream>>>(scores);
  attnw_k<<<1024, 256, 0, stream>>>(scores, out_attnw);

  // ax[h][b][t][d] = attn[b] @ x[b]   (per b: M=128, N=1024, K=1024) — split
  gemm_split<128, 128, 2, 2, false, 4><<<dim3(8, 1, 32), 256, 0, stream>>>(
      scores, x, (const float*)nullptr, ax, 128, 1024, 1024,
      131072L, 1048576L, 0L, 8192L, 1024);

  // ctx[bt][h*64+:64] = ax[h] @ wv_h^T + bv_h   (per h: M=256, N=64, K=1024) — split
  gemm_split<256, 64, 4, 1, true, 0><<<dim3(1, 1, 16), 256, 0, stream>>>(
      ax, in_w + 2097152, in_b + 2048, ctx, 256, 64, 1024,
      262144L, 65536L, 64L, 64L, 1024);

  // attn_out = ctx @ out_w^T + out_b   (M=256, N=1024, K=1024) — split
  gemm_split<128, 128, 2, 2, true, 0><<<dim3(8, 2, 1), 256, 0, stream>>>(
      ctx, out_w, out_b, attn_out, 256, 1024, 1024, 0, 0, 0, 0, 1024);

  hipMemsetAsync(ws + OFF_PSUM, 0, 16 * sizeof(float), stream);

  ln_gate_k<<<256, 256, 0, stream>>>(attn_out, gamma, beta, gate_w, yb, gates, Psum, fcnt);

  // h[e] = gelu(y @ w1[e] + b1[e])   (per e: M=256, N=4096, K=1024) — bf16
  gemm_bf16<128, 128, 2, 2, 2><<<dim3(32, 2, 8), 256, 0, stream>>>(
      yb, w1, b1, hb, 256, 4096, 1024, 0L, 4194304L, 4096L, 1048576L, 4096);

  // eo[e] = h[e] @ w2[e] + b2[e]   (per e: M=256, N=1024, K=4096) — bf16
  gemm_bf16<128, 128, 2, 2, 0><<<dim3(8, 2, 8), 256, 0, stream>>>(
      hb, w2, b2, eo, 256, 1024, 4096, 1048576L, 4194304L, 1024L, 262144L, 1024);

  combine_k<<<1024, 256, 0, stream>>>(attn_out, eo, gates, out_final);
  loss_k<<<1, 64, 0, stream>>>(Psum, fcnt, out_loss);
}

// Round 4
// 562.077 us; speedup vs baseline: 5.2221x; 1.6047x over previous
//
#include <hip/hip_runtime.h>
#include <hip/hip_bf16.h>
#include <math.h>

// B=32, S=1024, D=1024, H=16, dh=64, T=8, E=8, HID=4096
// Outputs fp32 concat: final(262144), moe_loss(1), attn_weights(262144)

using bf16x8  = __attribute__((ext_vector_type(8))) short;
using f32x4   = __attribute__((ext_vector_type(4))) float;
using short4v = __attribute__((ext_vector_type(4))) short;

__device__ inline short f2bf(float f) {
  unsigned u = __builtin_bit_cast(unsigned, f);
  u = (u + 0x7fffu + ((u >> 16) & 1u)) >> 16;
  return (short)u;
}

// ---------------- workspace layout (float offsets) ----------------
static constexpr long OFF_Q       = 0;         // 8192
static constexpr long OFF_QW      = 8192;      // 131072
static constexpr long OFF_QB      = 139264;    // 128
static constexpr long OFF_PSUM    = 139392;    // 8
static constexpr long OFF_FCNT    = 139400;    // 8
static constexpr long OFF_GATES   = 139408;    // 2048
static constexpr long OFF_CTX     = 141456;    // 262144 fp32
static constexpr long OFF_ATTNOUT = 403600;    // 262144 fp32
static constexpr long OFF_EO      = 665744;    // 2097152 fp32 [e][n][d]  (zeroed)
static constexpr long OFF_CTXP    = 2762896;   // 1048576 fp32 (4 partials)
static constexpr long OFF_AOP     = 3811472;   // 1048576 fp32 (4 partials)
static constexpr long OFF_SCORES  = 4860048;   // 4194304 fp32 [b][ht][s]
static constexpr long OFF_AX      = 9054352;   // 4194304 fp32 [h][b][t][d]
static constexpr long OFF_XT      = 13248656;  // 33554432 fp32 xT[b][d][s]; later aliased:
                                               //   W1T bf16 at XT (16777216 f), W2T bf16 at XT+16777216
static constexpr long OFF_YB      = 46803088;  // 131072 f = 262144 bf16
static constexpr long OFF_HB      = 46934160;  // 4194304 f = 8388608 bf16 [e][n][hid]
// end 51128464 floats = 204.5 MB

// ---------------- q: one wave per output element ----------------
__global__ __launch_bounds__(256) void compute_q_k(const float* __restrict__ probe,
                                                   const float* __restrict__ in_w,
                                                   const float* __restrict__ in_b,
                                                   float* __restrict__ q) {
  int wid = threadIdx.x >> 6, lane = threadIdx.x & 63;
  int idx = blockIdx.x * 4 + wid;   // t*1024 + d
  int t = idx >> 10, d = idx & 1023;
  const float* pr = probe + (long)t * 1024;
  const float* wr = in_w + (long)d * 1024;
  float s = 0.f;
  for (int k = lane * 4; k < 1024; k += 256) {
    float4 a = *(const float4*)&pr[k];
    float4 b = *(const float4*)&wr[k];
    s += a.x * b.x + a.y * b.y + a.z * b.z + a.w * b.w;
  }
  for (int o = 32; o; o >>= 1) s += __shfl_xor(s, o);
  if (!lane) q[idx] = s + in_b[d];
}

// ---------------- qw[ht][d] = sum_j (q[t][h*64+j]/8) * wk[h*64+j][d]; qb[ht] ----------------
__global__ __launch_bounds__(256) void compute_qw_k(const float* __restrict__ q,
                                                    const float* __restrict__ in_w,
                                                    const float* __restrict__ in_b,
                                                    float* __restrict__ qw,
                                                    float* __restrict__ qb) {
  int ht = blockIdx.x;           // h*8 + t
  int h = ht >> 3, t = ht & 7;
  int tid = threadIdx.x;
  __shared__ float qh[64];
  if (tid < 64) qh[tid] = q[t * 1024 + h * 64 + tid] * 0.125f;
  __syncthreads();
  if (tid == 0) {
    float s = 0.f;
    for (int j = 0; j < 64; ++j) s += qh[j] * in_b[1024 + h * 64 + j];
    qb[ht] = s;
  }
  const float* wk = in_w + 1048576;
  for (int d = tid; d < 1024; d += 256) {
    float a = 0.f;
    for (int j = 0; j < 64; ++j) a += qh[j] * wk[(long)(h * 64 + j) * 1024 + d];
    qw[(long)ht * 1024 + d] = a;
  }
}

// ---------------- transpose x: xT[b][d][s] = x[b][s][d]  (fp32) ----------------
__global__ __launch_bounds__(256) void transpose_x_k(const float* __restrict__ x,
                                                     float* __restrict__ xT) {
  __shared__ float T[64][65];
  const int b = blockIdx.z;
  const int d0 = blockIdx.x * 64, s0 = blockIdx.y * 64;
  const int tid = threadIdx.x;
  const float* xb = x + (long)b * 1048576;
  float* xtb = xT + (long)b * 1048576;
#pragma unroll
  for (int i = 0; i < 4; ++i) {
    int f = tid + i * 256;
    int sr = f >> 4, c4 = (f & 15) * 4;
    *(float4*)&T[sr][c4] = *(const float4*)&xb[(long)(s0 + sr) * 1024 + d0 + c4];
  }
  __syncthreads();
#pragma unroll
  for (int i = 0; i < 4; ++i) {
    int f = tid + i * 256;
    int dr = f >> 4, c4 = (f & 15) * 4;
    float4 v;
    v.x = T[c4 + 0][dr];
    v.y = T[c4 + 1][dr];
    v.z = T[c4 + 2][dr];
    v.w = T[c4 + 3][dr];
    *(float4*)&xtb[(long)(d0 + dr) * 1024 + s0 + c4] = v;
  }
}

// ---------------- transpose+convert weights: out[z][n][k] = bf16(in[z][k][n]) ----------------
__global__ __launch_bounds__(256) void transpose_w_k(const float* __restrict__ in,
                                                     short* __restrict__ out,
                                                     int K, int N) {
  __shared__ float T[64][65];
  const int z = blockIdx.z;
  const int n0 = blockIdx.x * 64, k0 = blockIdx.y * 64;
  const int tid = threadIdx.x;
  const float* ip = in + (long)z * K * N;
  short* op = out + (long)z * K * N;
#pragma unroll
  for (int i = 0; i < 4; ++i) {
    int f = tid + i * 256;
    int kr = f >> 4, c4 = (f & 15) * 4;
    *(float4*)&T[kr][c4] = *(const float4*)&ip[(long)(k0 + kr) * N + n0 + c4];
  }
  __syncthreads();
#pragma unroll
  for (int i = 0; i < 2; ++i) {
    int f = tid + i * 256;
    int nr = f >> 3, c8 = (f & 7) * 8;
    bf16x8 v;
#pragma unroll
    for (int j = 0; j < 8; ++j) v[j] = f2bf(T[c8 + j][nr]);
    *(bf16x8*)&op[(long)(n0 + nr) * K + k0 + c8] = v;
  }
}

// ---------------- split-bf16 MFMA GEMM (fp32-grade), reg-prefetch ----------------
// A: M x K fp32 row-major (lda). B: N x K fp32 row-major (ldb). Trunc-split hi/lo.
// z -> (zo = z/KS, kc = z%KS); A,B get column offset kc*K. AKB: add kbias[k] to A.
// EPI: 0 plain fp32 C[m*ldc+n]; 1 scores scatter +bias; 4 ax scatter
template<int WM, int WN, int KS, bool AKB, int EPI>
__global__ __launch_bounds__(WM * WN * 64)
void gemm_ss(const float* __restrict__ Ap, const float* __restrict__ Bp,
             const float* __restrict__ biasp, const float* __restrict__ kbias,
             float* __restrict__ Cp,
             int lda, int ldb, int K, long zA, long zB, long zBias, long zC, long ZKC, int ldc) {
  constexpr int BM = WM * 64, BN = WN * 64, BK = 32, NT = WM * WN * 64, PK = 40;
  constexpr int LA = BM * BK / (NT * 4), LB = BN * BK / (NT * 4);
  const int z = blockIdx.z, zo = z / KS, kc = z % KS;
  const float* A = Ap + zA * zo + (long)kc * K;
  const float* B = Bp + zB * zo + (long)kc * K;
  const float* bias = biasp + zBias * zo;
  const float* kb = kbias + (long)kc * K;
  float* C = Cp + zC * zo + ZKC * kc;
  const int tid = threadIdx.x;
  const int m0 = blockIdx.y * BM, n0 = blockIdx.x * BN;
  __shared__ short Ah[BM][PK], Al[BM][PK], Bh[BN][PK], Bl[BN][PK];

  f32x4 acc[4][4];
#pragma unroll
  for (int i = 0; i < 4; ++i)
#pragma unroll
    for (int j = 0; j < 4; ++j)
#pragma unroll
      for (int qq = 0; qq < 4; ++qq) acc[i][j][qq] = 0.f;

  const int wid = tid >> 6, lane = tid & 63;
  const int wm = wid % WM, wn = wid / WM;
  const int r = lane & 15, kg = (lane >> 4) * 8;

  float4 ra[LA], rb[LB];

  auto loadT = [&](int k0) {
#pragma unroll
    for (int i = 0; i < LA; ++i) {
      int f = tid + i * NT;
      int m = f >> 3, k4 = (f & 7) * 4;
      ra[i] = *(const float4*)&A[(long)(m0 + m) * lda + k0 + k4];
      if (AKB) {
        float4 kv = *(const float4*)&kb[k0 + k4];
        ra[i].x += kv.x; ra[i].y += kv.y; ra[i].z += kv.z; ra[i].w += kv.w;
      }
    }
#pragma unroll
    for (int i = 0; i < LB; ++i) {
      int f = tid + i * NT;
      int n = f >> 3, k4 = (f & 7) * 4;
      rb[i] = *(const float4*)&B[(long)(n0 + n) * ldb + k0 + k4];
    }
  };

  auto storeT = [&]() {
#pragma unroll
    for (int i = 0; i < LA; ++i) {
      int f = tid + i * NT;
      int m = f >> 3, k4 = (f & 7) * 4;
      short4v h, l;
      float vv[4] = {ra[i].x, ra[i].y, ra[i].z, ra[i].w};
#pragma unroll
      for (int j = 0; j < 4; ++j) {
        unsigned u = __builtin_bit_cast(unsigned, vv[j]);
        h[j] = (short)(u >> 16);
        l[j] = f2bf(vv[j] - __builtin_bit_cast(float, u & 0xFFFF0000u));
      }
      *(short4v*)&Ah[m][k4] = h;
      *(short4v*)&Al[m][k4] = l;
    }
#pragma unroll
    for (int i = 0; i < LB; ++i) {
      int f = tid + i * NT;
      int n = f >> 3, k4 = (f & 7) * 4;
      short4v h, l;
      float vv[4] = {rb[i].x, rb[i].y, rb[i].z, rb[i].w};
#pragma unroll
      for (int j = 0; j < 4; ++j) {
        unsigned u = __builtin_bit_cast(unsigned, vv[j]);
        h[j] = (short)(u >> 16);
        l[j] = f2bf(vv[j] - __builtin_bit_cast(float, u & 0xFFFF0000u));
      }
      *(short4v*)&Bh[n][k4] = h;
      *(short4v*)&Bl[n][k4] = l;
    }
  };

  loadT(0);
  for (int k0 = 0; k0 < K; k0 += BK) {
    storeT();
    __syncthreads();
    if (k0 + BK < K) loadT(k0 + BK);
    bf16x8 ah[4], al[4], bh[4], bl[4];
#pragma unroll
    for (int i = 0; i < 4; ++i) {
      ah[i] = *(const bf16x8*)&Ah[wm * 64 + i * 16 + r][kg];
      al[i] = *(const bf16x8*)&Al[wm * 64 + i * 16 + r][kg];
    }
#pragma unroll
    for (int j = 0; j < 4; ++j) {
      bh[j] = *(const bf16x8*)&Bh[wn * 64 + j * 16 + r][kg];
      bl[j] = *(const bf16x8*)&Bl[wn * 64 + j * 16 + r][kg];
    }
#pragma unroll
    for (int i = 0; i < 4; ++i)
#pragma unroll
      for (int j = 0; j < 4; ++j) {
        acc[i][j] = __builtin_amdgcn_mfma_f32_16x16x32_bf16(ah[i], bh[j], acc[i][j], 0, 0, 0);
        acc[i][j] = __builtin_amdgcn_mfma_f32_16x16x32_bf16(ah[i], bl[j], acc[i][j], 0, 0, 0);
        acc[i][j] = __builtin_amdgcn_mfma_f32_16x16x32_bf16(al[i], bh[j], acc[i][j], 0, 0, 0);
      }
    __syncthreads();
  }

  const int q4 = (lane >> 4) * 4;
#pragma unroll
  for (int i = 0; i < 4; ++i) {
    int gmb = m0 + wm * 64 + i * 16 + q4;
#pragma unroll
    for (int j = 0; j < 4; ++j) {
      int gn = n0 + wn * 64 + j * 16 + r;
#pragma unroll
      for (int qq = 0; qq < 4; ++qq) {
        float v = acc[i][j][qq];
        int m = gmb + qq;
        if constexpr (EPI == 0) {
          C[(long)m * ldc + gn] = v;
        } else if constexpr (EPI == 1) {
          Cp[(long)(m >> 10) * 131072 + (long)gn * 1024 + (m & 1023)] = v + bias[gn];
        } else {  // EPI == 4
          C[(long)(m >> 3) * 262144 + (long)(m & 7) * 1024 + gn] = v;
        }
      }
    }
  }
}

// ---------------- bf16 MFMA GEMM (both operands bf16 N x K / M x K), reg-prefetch ----------------
// EPI: 2 gelu->bf16 +bias; 5 atomicAdd fp32 (no bias)
template<int WM, int WN, int KS, int EPI>
__global__ __launch_bounds__(WM * WN * 64)
void gemm_bb(const short* __restrict__ Ap, const short* __restrict__ Bp,
             const float* __restrict__ biasp, void* __restrict__ Cp,
             int lda, int ldb, int K, long zA, long zB, long zBias, long zC, int ldc) {
  constexpr int BM = WM * 64, BN = WN * 64, BK = 64, NT = WM * WN * 64, PK = 72;
  constexpr int LA = BM * BK / (NT * 8), LB = BN * BK / (NT * 8);
  const int z = blockIdx.z, zo = z / KS, kc = z % KS;
  const short* A = Ap + zA * zo + (long)kc * K;
  const short* B = Bp + zB * zo + (long)kc * K;
  const float* bias = biasp + zBias * zo;
  const int tid = threadIdx.x;
  const int m0 = blockIdx.y * BM, n0 = blockIdx.x * BN;
  __shared__ short As[BM][PK], Bs[BN][PK];

  f32x4 acc[4][4];
#pragma unroll
  for (int i = 0; i < 4; ++i)
#pragma unroll
    for (int j = 0; j < 4; ++j)
#pragma unroll
      for (int qq = 0; qq < 4; ++qq) acc[i][j][qq] = 0.f;

  const int wid = tid >> 6, lane = tid & 63;
  const int wm = wid % WM, wn = wid / WM;
  const int r = lane & 15, kg = (lane >> 4) * 8;

  bf16x8 ra[LA], rb[LB];

  auto loadT = [&](int k0) {
#pragma unroll
    for (int i = 0; i < LA; ++i) {
      int f = tid + i * NT;
      int m = f >> 3, k8 = (f & 7) * 8;
      ra[i] = *(const bf16x8*)&A[(long)(m0 + m) * lda + k0 + k8];
    }
#pragma unroll
    for (int i = 0; i < LB; ++i) {
      int f = tid + i * NT;
      int n = f >> 3, k8 = (f & 7) * 8;
      rb[i] = *(const bf16x8*)&B[(long)(n0 + n) * ldb + k0 + k8];
    }
  };

  loadT(0);
  for (int k0 = 0; k0 < K; k0 += BK) {
#pragma unroll
    for (int i = 0; i < LA; ++i) {
      int f = tid + i * NT;
      int m = f >> 3, k8 = (f & 7) * 8;
      *(bf16x8*)&As[m][k8] = ra[i];
    }
#pragma unroll
    for (int i = 0; i < LB; ++i) {
      int f = tid + i * NT;
      int n = f >> 3, k8 = (f & 7) * 8;
      *(bf16x8*)&Bs[n][k8] = rb[i];
    }
    __syncthreads();
    if (k0 + BK < K) loadT(k0 + BK);
#pragma unroll
    for (int kk = 0; kk < 2; ++kk) {
      bf16x8 af[4], bfr[4];
#pragma unroll
      for (int i = 0; i < 4; ++i) af[i] = *(const bf16x8*)&As[wm * 64 + i * 16 + r][kk * 32 + kg];
#pragma unroll
      for (int j = 0; j < 4; ++j) bfr[j] = *(const bf16x8*)&Bs[wn * 64 + j * 16 + r][kk * 32 + kg];
#pragma unroll
      for (int i = 0; i < 4; ++i)
#pragma unroll
        for (int j = 0; j < 4; ++j)
          acc[i][j] = __builtin_amdgcn_mfma_f32_16x16x32_bf16(af[i], bfr[j], acc[i][j], 0, 0, 0);
    }
    __syncthreads();
  }

  const int q4 = (lane >> 4) * 4;
#pragma unroll
  for (int i = 0; i < 4; ++i) {
    int gmb = m0 + wm * 64 + i * 16 + q4;
#pragma unroll
    for (int j = 0; j < 4; ++j) {
      int gn = n0 + wn * 64 + j * 16 + r;
#pragma unroll
      for (int qq = 0; qq < 4; ++qq) {
        float v = acc[i][j][qq];
        int m = gmb + qq;
        if constexpr (EPI == 2) {
          float u = v + bias[gn];
          u = 0.5f * u * (1.0f + erff(u * 0.70710678118654752f));
          ((short*)Cp + zC * zo)[(long)m * ldc + gn] = f2bf(u);
        } else {  // EPI == 5
          atomicAdd(&((float*)Cp + zC * zo)[(long)m * ldc + gn], v);
        }
      }
    }
  }
}

// ---------------- reduce 4 partials ----------------
__global__ __launch_bounds__(256) void reduce4_k(const float* __restrict__ p,
                                                 float* __restrict__ out) {
  int i = (blockIdx.x * 256 + threadIdx.x) * 4;
  float4 a = *(const float4*)&p[i];
  float4 b = *(const float4*)&p[i + 262144];
  float4 c = *(const float4*)&p[i + 524288];
  float4 d = *(const float4*)&p[i + 786432];
  float4 o;
  o.x = a.x + b.x + c.x + d.x;
  o.y = a.y + b.y + c.y + d.y;
  o.z = a.z + b.z + c.z + d.z;
  o.w = a.w + b.w + c.w + d.w;
  *(float4*)&out[i] = o;
}

// ---------------- softmax over s (in place) ----------------
__global__ __launch_bounds__(256) void softmax_k(float* __restrict__ scores) {
  long row = blockIdx.x;
  float* p = scores + row * 1024;
  int tid = threadIdx.x;
  int wid = tid >> 6, lane = tid & 63;
  float v[4];
  float mx = -1e30f;
#pragma unroll
  for (int i = 0; i < 4; ++i) { v[i] = p[tid + i * 256]; mx = fmaxf(mx, v[i]); }
  for (int o = 32; o; o >>= 1) mx = fmaxf(mx, __shfl_xor(mx, o));
  __shared__ float sm[4];
  __shared__ float ss[4];
  if (!lane) sm[wid] = mx;
  __syncthreads();
  mx = fmaxf(fmaxf(sm[0], sm[1]), fmaxf(sm[2], sm[3]));
  float s = 0.f;
#pragma unroll
  for (int i = 0; i < 4; ++i) { v[i] = expf(v[i] - mx); s += v[i]; }
  for (int o = 32; o; o >>= 1) s += __shfl_xor(s, o);
  if (!lane) ss[wid] = s;
  __syncthreads();
  s = ss[0] + ss[1] + ss[2] + ss[3];
  float inv = 1.0f / s;
#pragma unroll
  for (int i = 0; i < 4; ++i) p[tid + i * 256] = v[i] * inv;
}

// ---------------- attn_weights[b][t][s] = mean_h attn ----------------
__global__ __launch_bounds__(256) void attnw_k(const float* __restrict__ attn,
                                               float* __restrict__ outw) {
  int idx = blockIdx.x * 256 + threadIdx.x;
  int b = idx >> 13;
  int r = idx & 8191;
  int t = r >> 10, s = r & 1023;
  const float* p = attn + (long)b * 131072 + (long)t * 1024 + s;
  float acc = 0.f;
#pragma unroll
  for (int h = 0; h < 16; ++h) acc += p[(long)h * 8192];
  outw[idx] = acc * (1.0f / 16.0f);
}

// ---------------- layernorm + gate softmax + top2 (out_b folded in) ----------------
__global__ __launch_bounds__(256) void ln_gate_k(const float* __restrict__ attn_out,
                                                 const float* __restrict__ out_b,
                                                 const float* __restrict__ gamma,
                                                 const float* __restrict__ beta,
                                                 const float* __restrict__ gate_w,
                                                 short* __restrict__ yb,
                                                 float* __restrict__ gates,
                                                 float* __restrict__ Psum,
                                                 float* __restrict__ fcnt) {
  int row = blockIdx.x;        // n = b*8 + t
  int t = row & 7;
  int tid = threadIdx.x;
  int wid = tid >> 6, lane = tid & 63;
  const float* xr = attn_out + (long)row * 1024;
  float vals[4];
  float s = 0.f, sq = 0.f;
#pragma unroll
  for (int i = 0; i < 4; ++i) {
    int d = tid + i * 256;
    float v = xr[d] + out_b[d];
    vals[i] = v;
    s += v;
    sq += v * v;
  }
  for (int o = 32; o; o >>= 1) { s += __shfl_xor(s, o); sq += __shfl_xor(sq, o); }
  __shared__ float rs[4], rss[4];
  if (!lane) { rs[wid] = s; rss[wid] = sq; }
  __syncthreads();
  s = rs[0] + rs[1] + rs[2] + rs[3];
  sq = rss[0] + rss[1] + rss[2] + rss[3];
  float mu = s * (1.0f / 1024.0f);
  float var = sq * (1.0f / 1024.0f) - mu * mu;
  float rstd = rsqrtf(var + 1e-5f);
  __shared__ float yrow[1024];
#pragma unroll
  for (int i = 0; i < 4; ++i) {
    int d = tid + i * 256;
    float yv = (vals[i] - mu) * rstd * gamma[d] + beta[d];
    yb[(long)row * 1024 + d] = f2bf(yv);
    yrow[d] = yv;
  }
  __syncthreads();
  int e = tid & 7;
  int g = tid >> 3;
  float acc = 0.f;
  const float* gw = gate_w + (long)t * 8192;
  for (int d = g; d < 1024; d += 32) acc += yrow[d] * gw[d * 8 + e];
  __shared__ float part[256];
  __shared__ float lsh[8];
  part[tid] = acc;
  __syncthreads();
  if (tid < 8) {
    float l = 0.f;
    for (int gg = 0; gg < 32; ++gg) l += part[gg * 8 + tid];
    lsh[tid] = l;
  }
  __syncthreads();
  if (tid == 0) {
    float p[8];
    float mx = -1e30f;
    for (int k = 0; k < 8; ++k) mx = fmaxf(mx, lsh[k]);
    float sum = 0.f;
    for (int k = 0; k < 8; ++k) { p[k] = expf(lsh[k] - mx); sum += p[k]; }
    float inv = 1.0f / sum;
    for (int k = 0; k < 8; ++k) p[k] *= inv;
    int i0 = 0;
    for (int k = 1; k < 8; ++k) if (p[k] > p[i0]) i0 = k;
    int i1 = -1;
    for (int k = 0; k < 8; ++k) if (k != i0 && (i1 < 0 || p[k] > p[i1])) i1 = k;
    float tot = p[i0] + p[i1];
    for (int k = 0; k < 8; ++k)
      gates[(long)row * 8 + k] = (k == i0) ? p[i0] / tot : (k == i1) ? p[i1] / tot : 0.f;
    for (int k = 0; k < 8; ++k) atomicAdd(&Psum[k], p[k]);
    atomicAdd(&fcnt[i0], 1.0f);
    atomicAdd(&fcnt[i1], 1.0f);
  }
}

// ---------------- final = attn_out + out_b + sum_e g_e * (eo[e] + b2[e]) ----------------
__global__ __launch_bounds__(256) void combine_k(const float* __restrict__ attn_out,
                                                 const float* __restrict__ out_b,
                                                 const float* __restrict__ eo,
                                                 const float* __restrict__ b2,
                                                 const float* __restrict__ gates,
                                                 float* __restrict__ outp) {
  int idx = blockIdx.x * 256 + threadIdx.x;
  int n = idx >> 10, d = idx & 1023;
  float v = attn_out[idx] + out_b[d];
  const float* g = gates + (long)n * 8;
#pragma unroll
  for (int e = 0; e < 8; ++e) {
    float ge = g[e];
    if (ge != 0.f) v += ge * (eo[(long)e * 262144 + idx] + b2[e * 1024 + d]);
  }
  outp[idx] = v;
}

__global__ void loss_k(const float* __restrict__ Psum, const float* __restrict__ fcnt,
                       float* __restrict__ out) {
  if (threadIdx.x == 0) {
    float l = 0.f;
    for (int e = 0; e < 8; ++e) l += (fcnt[e] * (1.0f / 256.0f)) * (Psum[e] * (1.0f / 256.0f));
    out[0] = 8.0f * l;
  }
}

extern "C" void kernel_launch(void* const* d_in, const int* in_sizes, int n_in,
                              void* d_out, int out_size, void* d_ws, size_t ws_size,
                              hipStream_t stream) {
  const float* x      = (const float*)d_in[0];
  const float* probe  = (const float*)d_in[1];
  const float* in_w   = (const float*)d_in[2];
  const float* in_b   = (const float*)d_in[3];
  const float* out_w  = (const float*)d_in[4];
  const float* out_b  = (const float*)d_in[5];
  const float* gamma  = (const float*)d_in[6];
  const float* beta   = (const float*)d_in[7];
  const float* gate_w = (const float*)d_in[8];
  const float* w1     = (const float*)d_in[9];
  const float* b1     = (const float*)d_in[10];
  const float* w2     = (const float*)d_in[11];
  const float* b2     = (const float*)d_in[12];

  float* ws = (float*)d_ws;
  float* q        = ws + OFF_Q;
  float* qw       = ws + OFF_QW;
  float* qb       = ws + OFF_QB;
  float* Psum     = ws + OFF_PSUM;
  float* fcnt     = ws + OFF_FCNT;
  float* gates    = ws + OFF_GATES;
  float* ctx      = ws + OFF_CTX;
  float* attn_out = ws + OFF_ATTNOUT;
  float* eo       = ws + OFF_EO;
  float* ctxp     = ws + OFF_CTXP;
  float* aop      = ws + OFF_AOP;
  float* scores   = ws + OFF_SCORES;
  float* ax       = ws + OFF_AX;
  float* xT       = ws + OFF_XT;
  short* w1T      = (short*)(ws + OFF_XT);              // aliases xT (used after ax GEMM)
  short* w2T      = (short*)(ws + OFF_XT + 16777216);
  short* yb       = (short*)(ws + OFF_YB);
  short* hb       = (short*)(ws + OFF_HB);

  float* out_final = (float*)d_out;
  float* out_loss  = out_final + 262144;
  float* out_attnw = out_loss + 1;

  hipMemsetAsync(ws + OFF_PSUM, 0, 16 * sizeof(float), stream);
  hipMemsetAsync(eo, 0, 2097152 * sizeof(float), stream);

  compute_q_k<<<2048, 256, 0, stream>>>(probe, in_w, in_b, q);
  compute_qw_k<<<128, 256, 0, stream>>>(q, in_w, in_b, qw, qb);

  // xT[b][d][s] fp32
  transpose_x_k<<<dim3(16, 16, 32), 256, 0, stream>>>(x, xT);

  // scores[b][ht][s] = x @ qw^T + qb   (M=32768, N=128, K=1024) split
  gemm_ss<2, 2, 1, false, 1><<<dim3(1, 256, 1), 256, 0, stream>>>(
      x, qw, qb, x /*unused*/, scores, 1024, 1024, 1024, 0, 0, 0, 0, 0, 1024);

  softmax_k<<<4096, 256, 0, stream>>>(scores);
  attnw_k<<<1024, 256, 0, stream>>>(scores, out_attnw);

  // ax[h][b][t][d] = attn[b] @ xT[b]^T  (per b: M=128, N=1024, K=1024) split
  gemm_ss<2, 2, 1, false, 4><<<dim3(8, 1, 32), 256, 0, stream>>>(
      scores, xT, qb /*unused*/, x /*unused*/, ax, 1024, 1024, 1024,
      131072L, 1048576L, 0L, 8192L, 0L, 1024);

  // weight transposes (xT dead now; w1T/w2T alias it)
  transpose_w_k<<<dim3(64, 16, 8), 256, 0, stream>>>(w1, w1T, 1024, 4096);
  transpose_w_k<<<dim3(16, 64, 8), 256, 0, stream>>>(w2, w2T, 4096, 1024);

  // ctx partials: per (h, kc): M=256, N=64, K=256 split -> ctxp[kc][n][h*64+:]
  gemm_ss<1, 1, 4, false, 0><<<dim3(1, 4, 64), 64, 0, stream>>>(
      ax, in_w + 2097152, qb /*unused*/, x /*unused*/, ctxp, 1024, 1024, 256,
      262144L, 65536L, 0L, 64L, 262144L, 1024);
  reduce4_k<<<256, 256, 0, stream>>>(ctxp, ctx);

  // attn_out partials: A = ctx + bv(kbias), B = out_w  (M=256, N=1024, K=256 x4) split
  gemm_ss<1, 1, 4, true, 0><<<dim3(16, 4, 4), 64, 0, stream>>>(
      ctx, out_w, qb /*unused*/, in_b + 2048, aop, 1024, 1024, 256,
      0L, 0L, 0L, 0L, 262144L, 1024);
  reduce4_k<<<256, 256, 0, stream>>>(aop, attn_out);

  // layernorm + gate + top2 (adds out_b internally)
  ln_gate_k<<<256, 256, 0, stream>>>(attn_out, out_b, gamma, beta, gate_w, yb, gates, Psum, fcnt);

  // h[e] = gelu(yb @ w1T[e]^T + b1[e])  (M=256, N=4096, K=1024) bf16
  gemm_bb<2, 2, 1, 2><<<dim3(32, 2, 8), 256, 0, stream>>>(
      yb, w1T, b1, hb, 1024, 1024, 1024, 0L, 4194304L, 4096L, 1048576L, 4096);

  // eo[e] += hb @ w2T[e]^T  (M=256, N=1024, K=1024 x4 ksplit, atomic) bf16
  gemm_bb<2, 2, 4, 5><<<dim3(8, 2, 32), 256, 0, stream>>>(
      hb, w2T, b1 /*unused*/, eo, 4096, 4096, 1024, 1048576L, 4194304L, 0L, 262144L, 1024);

  combine_k<<<1024, 256, 0, stream>>>(attn_out, out_b, eo, b2, gates, out_final);
  loss_k<<<1, 64, 0, stream>>>(Psum, fcnt, out_loss);
}

// Round 5
// 482.000 us; speedup vs baseline: 6.0896x; 1.1661x over previous
//
#include <hip/hip_runtime.h>
#include <hip/hip_bf16.h>
#include <math.h>

// B=32, S=1024, D=1024, H=16, dh=64, T=8, E=8, HID=4096
// Outputs fp32 concat: final(262144), moe_loss(1), attn_weights(262144)

using bf16x8  = __attribute__((ext_vector_type(8))) short;
using f32x4   = __attribute__((ext_vector_type(4))) float;
using short4v = __attribute__((ext_vector_type(4))) short;

__device__ inline short f2bf(float f) {
  unsigned u = __builtin_bit_cast(unsigned, f);
  u = (u + 0x7fffu + ((u >> 16) & 1u)) >> 16;
  return (short)u;
}

// ---------------- workspace layout (float offsets) ----------------
static constexpr long OFF_Q       = 0;         // 8192
static constexpr long OFF_QW      = 8192;      // 131072
static constexpr long OFF_QB      = 139264;    // 128
static constexpr long OFF_PSUM    = 139392;    // 8
static constexpr long OFF_FCNT    = 139400;    // 8
static constexpr long OFF_GATES   = 139408;    // 2048
static constexpr long OFF_CTX     = 141456;    // 262144 fp32
static constexpr long OFF_ATTNOUT = 403600;    // 262144 fp32
static constexpr long OFF_EO      = 665744;    // 2097152 fp32 [e][n][d]  (zeroed)
static constexpr long OFF_CTXP    = 2762896;   // 1048576 fp32 (4 partials)
static constexpr long OFF_AOP     = 3811472;   // 1048576 fp32 (4 partials)
static constexpr long OFF_SCORES  = 4860048;   // 4194304 fp32 [b][ht][s]
static constexpr long OFF_AX      = 9054352;   // 4194304 fp32 [h][b][t][d]
static constexpr long OFF_XT      = 13248656;  // 33554432 fp32 xT[b][d][s]; later aliased:
                                               //   W1T bf16 at XT (16777216 f), W2T bf16 at XT+16777216
static constexpr long OFF_YB      = 46803088;  // 131072 f = 262144 bf16
static constexpr long OFF_HB      = 46934160;  // 4194304 f = 8388608 bf16 [e][n][hid]
// end 51128464 floats = 204.5 MB

// ---------------- q: one wave per output element ----------------
__global__ __launch_bounds__(256) void compute_q_k(const float* __restrict__ probe,
                                                   const float* __restrict__ in_w,
                                                   const float* __restrict__ in_b,
                                                   float* __restrict__ q) {
  int wid = threadIdx.x >> 6, lane = threadIdx.x & 63;
  int idx = blockIdx.x * 4 + wid;   // t*1024 + d
  int t = idx >> 10, d = idx & 1023;
  const float* pr = probe + (long)t * 1024;
  const float* wr = in_w + (long)d * 1024;
  float s = 0.f;
  for (int k = lane * 4; k < 1024; k += 256) {
    float4 a = *(const float4*)&pr[k];
    float4 b = *(const float4*)&wr[k];
    s += a.x * b.x + a.y * b.y + a.z * b.z + a.w * b.w;
  }
  for (int o = 32; o; o >>= 1) s += __shfl_xor(s, o);
  if (!lane) q[idx] = s + in_b[d];
}

// ---------------- qw[h*8+t][d] = sum_j (q[t][h*64+j]/8) * wk[h*64+j][d]; qb ----------------
// grid (4, 16): d-chunk of 256, h. Coalesced wk rows, LDS-broadcast q.
__global__ __launch_bounds__(256) void compute_qw_k(const float* __restrict__ q,
                                                    const float* __restrict__ in_w,
                                                    const float* __restrict__ in_b,
                                                    float* __restrict__ qw,
                                                    float* __restrict__ qb) {
  const int h = blockIdx.y;
  const int tid = threadIdx.x;
  const int d = blockIdx.x * 256 + tid;
  __shared__ float qh[8][64];
  if (tid < 64) {
#pragma unroll
    for (int t = 0; t < 8; ++t) qh[t][tid] = q[t * 1024 + h * 64 + tid] * 0.125f;
  }
  __syncthreads();
  const float* wk = in_w + 1048576 + (long)h * 64 * 1024;
  float acc[8];
#pragma unroll
  for (int t = 0; t < 8; ++t) acc[t] = 0.f;
  for (int j = 0; j < 64; ++j) {
    float w = wk[(long)j * 1024 + d];
#pragma unroll
    for (int t = 0; t < 8; ++t) acc[t] += qh[t][j] * w;
  }
#pragma unroll
  for (int t = 0; t < 8; ++t) qw[(long)(h * 8 + t) * 1024 + d] = acc[t];
  if (blockIdx.x == 0 && tid < 8) {
    float s = 0.f;
    for (int j = 0; j < 64; ++j) s += qh[tid][j] * in_b[1024 + h * 64 + j];
    qb[h * 8 + tid] = s;
  }
}

// ---------------- transpose x: xT[b][d][s] = x[b][s][d]  (fp32) ----------------
__global__ __launch_bounds__(256) void transpose_x_k(const float* __restrict__ x,
                                                     float* __restrict__ xT) {
  __shared__ float T[64][65];
  const int b = blockIdx.z;
  const int d0 = blockIdx.x * 64, s0 = blockIdx.y * 64;
  const int tid = threadIdx.x;
  const float* xb = x + (long)b * 1048576;
  float* xtb = xT + (long)b * 1048576;
#pragma unroll
  for (int i = 0; i < 4; ++i) {
    int f = tid + i * 256;
    int sr = f >> 4, c4 = (f & 15) * 4;
    *(float4*)&T[sr][c4] = *(const float4*)&xb[(long)(s0 + sr) * 1024 + d0 + c4];
  }
  __syncthreads();
#pragma unroll
  for (int i = 0; i < 4; ++i) {
    int f = tid + i * 256;
    int dr = f >> 4, c4 = (f & 15) * 4;
    float4 v;
    v.x = T[c4 + 0][dr];
    v.y = T[c4 + 1][dr];
    v.z = T[c4 + 2][dr];
    v.w = T[c4 + 3][dr];
    *(float4*)&xtb[(long)(d0 + dr) * 1024 + s0 + c4] = v;
  }
}

// ---------------- transpose+convert weights: out[z][n][k] = bf16(in[z][k][n]) ----------------
__global__ __launch_bounds__(256) void transpose_w_k(const float* __restrict__ in,
                                                     short* __restrict__ out,
                                                     int K, int N) {
  __shared__ float T[64][65];
  const int z = blockIdx.z;
  const int n0 = blockIdx.x * 64, k0 = blockIdx.y * 64;
  const int tid = threadIdx.x;
  const float* ip = in + (long)z * K * N;
  short* op = out + (long)z * K * N;
#pragma unroll
  for (int i = 0; i < 4; ++i) {
    int f = tid + i * 256;
    int kr = f >> 4, c4 = (f & 15) * 4;
    *(float4*)&T[kr][c4] = *(const float4*)&ip[(long)(k0 + kr) * N + n0 + c4];
  }
  __syncthreads();
#pragma unroll
  for (int i = 0; i < 2; ++i) {
    int f = tid + i * 256;
    int nr = f >> 3, c8 = (f & 7) * 8;
    bf16x8 v;
#pragma unroll
    for (int j = 0; j < 8; ++j) v[j] = f2bf(T[c8 + j][nr]);
    *(bf16x8*)&op[(long)(n0 + nr) * K + k0 + c8] = v;
  }
}

// ---------------- split-bf16 MFMA GEMM (fp32-grade), reg-prefetch ----------------
// A: M x K fp32 row-major (lda). B: N x K fp32 row-major (ldb). Trunc-split hi/lo.
// z -> (zo = z/KS, kc = z%KS); A,B get column offset kc*K. AKB: add kbias[k] to A.
// EPI: 0 plain fp32 C[m*ldc+n]; 1 scores scatter +bias; 4 ax scatter
template<int WM, int WN, int KS, bool AKB, int EPI>
__global__ __launch_bounds__(WM * WN * 64)
void gemm_ss(const float* __restrict__ Ap, const float* __restrict__ Bp,
             const float* __restrict__ biasp, const float* __restrict__ kbias,
             float* __restrict__ Cp,
             int lda, int ldb, int K, long zA, long zB, long zBias, long zC, long ZKC, int ldc) {
  constexpr int BM = WM * 64, BN = WN * 64, BK = 32, NT = WM * WN * 64, PK = 40;
  constexpr int LA = BM * BK / (NT * 4), LB = BN * BK / (NT * 4);
  const int z = blockIdx.z, zo = z / KS, kc = z % KS;
  const float* A = Ap + zA * zo + (long)kc * K;
  const float* B = Bp + zB * zo + (long)kc * K;
  const float* bias = biasp + zBias * zo;
  const float* kb = kbias + (long)kc * K;
  float* C = Cp + zC * zo + ZKC * kc;
  const int tid = threadIdx.x;
  const int m0 = blockIdx.y * BM, n0 = blockIdx.x * BN;
  __shared__ short Ah[BM][PK], Al[BM][PK], Bh[BN][PK], Bl[BN][PK];

  f32x4 acc[4][4];
#pragma unroll
  for (int i = 0; i < 4; ++i)
#pragma unroll
    for (int j = 0; j < 4; ++j)
#pragma unroll
      for (int qq = 0; qq < 4; ++qq) acc[i][j][qq] = 0.f;

  const int wid = tid >> 6, lane = tid & 63;
  const int wm = wid % WM, wn = wid / WM;
  const int r = lane & 15, kg = (lane >> 4) * 8;

  float4 ra[LA], rb[LB];

  auto loadT = [&](int k0) {
#pragma unroll
    for (int i = 0; i < LA; ++i) {
      int f = tid + i * NT;
      int m = f >> 3, k4 = (f & 7) * 4;
      ra[i] = *(const float4*)&A[(long)(m0 + m) * lda + k0 + k4];
      if (AKB) {
        float4 kv = *(const float4*)&kb[k0 + k4];
        ra[i].x += kv.x; ra[i].y += kv.y; ra[i].z += kv.z; ra[i].w += kv.w;
      }
    }
#pragma unroll
    for (int i = 0; i < LB; ++i) {
      int f = tid + i * NT;
      int n = f >> 3, k4 = (f & 7) * 4;
      rb[i] = *(const float4*)&B[(long)(n0 + n) * ldb + k0 + k4];
    }
  };

  auto storeT = [&]() {
#pragma unroll
    for (int i = 0; i < LA; ++i) {
      int f = tid + i * NT;
      int m = f >> 3, k4 = (f & 7) * 4;
      short4v h, l;
      float vv[4] = {ra[i].x, ra[i].y, ra[i].z, ra[i].w};
#pragma unroll
      for (int j = 0; j < 4; ++j) {
        unsigned u = __builtin_bit_cast(unsigned, vv[j]);
        h[j] = (short)(u >> 16);
        l[j] = f2bf(vv[j] - __builtin_bit_cast(float, u & 0xFFFF0000u));
      }
      *(short4v*)&Ah[m][k4] = h;
      *(short4v*)&Al[m][k4] = l;
    }
#pragma unroll
    for (int i = 0; i < LB; ++i) {
      int f = tid + i * NT;
      int n = f >> 3, k4 = (f & 7) * 4;
      short4v h, l;
      float vv[4] = {rb[i].x, rb[i].y, rb[i].z, rb[i].w};
#pragma unroll
      for (int j = 0; j < 4; ++j) {
        unsigned u = __builtin_bit_cast(unsigned, vv[j]);
        h[j] = (short)(u >> 16);
        l[j] = f2bf(vv[j] - __builtin_bit_cast(float, u & 0xFFFF0000u));
      }
      *(short4v*)&Bh[n][k4] = h;
      *(short4v*)&Bl[n][k4] = l;
    }
  };

  loadT(0);
  for (int k0 = 0; k0 < K; k0 += BK) {
    storeT();
    __syncthreads();
    if (k0 + BK < K) loadT(k0 + BK);
    bf16x8 ah[4], al[4], bh[4], bl[4];
#pragma unroll
    for (int i = 0; i < 4; ++i) {
      ah[i] = *(const bf16x8*)&Ah[wm * 64 + i * 16 + r][kg];
      al[i] = *(const bf16x8*)&Al[wm * 64 + i * 16 + r][kg];
    }
#pragma unroll
    for (int j = 0; j < 4; ++j) {
      bh[j] = *(const bf16x8*)&Bh[wn * 64 + j * 16 + r][kg];
      bl[j] = *(const bf16x8*)&Bl[wn * 64 + j * 16 + r][kg];
    }
#pragma unroll
    for (int i = 0; i < 4; ++i)
#pragma unroll
      for (int j = 0; j < 4; ++j) {
        acc[i][j] = __builtin_amdgcn_mfma_f32_16x16x32_bf16(ah[i], bh[j], acc[i][j], 0, 0, 0);
        acc[i][j] = __builtin_amdgcn_mfma_f32_16x16x32_bf16(ah[i], bl[j], acc[i][j], 0, 0, 0);
        acc[i][j] = __builtin_amdgcn_mfma_f32_16x16x32_bf16(al[i], bh[j], acc[i][j], 0, 0, 0);
      }
    __syncthreads();
  }

  const int q4 = (lane >> 4) * 4;
#pragma unroll
  for (int i = 0; i < 4; ++i) {
    int gmb = m0 + wm * 64 + i * 16 + q4;
#pragma unroll
    for (int j = 0; j < 4; ++j) {
      int gn = n0 + wn * 64 + j * 16 + r;
#pragma unroll
      for (int qq = 0; qq < 4; ++qq) {
        float v = acc[i][j][qq];
        int m = gmb + qq;
        if constexpr (EPI == 0) {
          C[(long)m * ldc + gn] = v;
        } else if constexpr (EPI == 1) {
          Cp[(long)(m >> 10) * 131072 + (long)gn * 1024 + (m & 1023)] = v + bias[gn];
        } else {  // EPI == 4
          C[(long)(m >> 3) * 262144 + (long)(m & 7) * 1024 + gn] = v;
        }
      }
    }
  }
}

// ---------------- bf16 MFMA GEMM (both operands bf16 N x K / M x K), reg-prefetch ----------------
// EPI: 2 gelu->bf16 +bias; 5 atomicAdd fp32 (no bias)
template<int WM, int WN, int KS, int EPI>
__global__ __launch_bounds__(WM * WN * 64)
void gemm_bb(const short* __restrict__ Ap, const short* __restrict__ Bp,
             const float* __restrict__ biasp, void* __restrict__ Cp,
             int lda, int ldb, int K, long zA, long zB, long zBias, long zC, int ldc) {
  constexpr int BM = WM * 64, BN = WN * 64, BK = 64, NT = WM * WN * 64, PK = 72;
  constexpr int LA = BM * BK / (NT * 8), LB = BN * BK / (NT * 8);
  const int z = blockIdx.z, zo = z / KS, kc = z % KS;
  const short* A = Ap + zA * zo + (long)kc * K;
  const short* B = Bp + zB * zo + (long)kc * K;
  const float* bias = biasp + zBias * zo;
  const int tid = threadIdx.x;
  const int m0 = blockIdx.y * BM, n0 = blockIdx.x * BN;
  __shared__ short As[BM][PK], Bs[BN][PK];

  f32x4 acc[4][4];
#pragma unroll
  for (int i = 0; i < 4; ++i)
#pragma unroll
    for (int j = 0; j < 4; ++j)
#pragma unroll
      for (int qq = 0; qq < 4; ++qq) acc[i][j][qq] = 0.f;

  const int wid = tid >> 6, lane = tid & 63;
  const int wm = wid % WM, wn = wid / WM;
  const int r = lane & 15, kg = (lane >> 4) * 8;

  bf16x8 ra[LA], rb[LB];

  auto loadT = [&](int k0) {
#pragma unroll
    for (int i = 0; i < LA; ++i) {
      int f = tid + i * NT;
      int m = f >> 3, k8 = (f & 7) * 8;
      ra[i] = *(const bf16x8*)&A[(long)(m0 + m) * lda + k0 + k8];
    }
#pragma unroll
    for (int i = 0; i < LB; ++i) {
      int f = tid + i * NT;
      int n = f >> 3, k8 = (f & 7) * 8;
      rb[i] = *(const bf16x8*)&B[(long)(n0 + n) * ldb + k0 + k8];
    }
  };

  loadT(0);
  for (int k0 = 0; k0 < K; k0 += BK) {
#pragma unroll
    for (int i = 0; i < LA; ++i) {
      int f = tid + i * NT;
      int m = f >> 3, k8 = (f & 7) * 8;
      *(bf16x8*)&As[m][k8] = ra[i];
    }
#pragma unroll
    for (int i = 0; i < LB; ++i) {
      int f = tid + i * NT;
      int n = f >> 3, k8 = (f & 7) * 8;
      *(bf16x8*)&Bs[n][k8] = rb[i];
    }
    __syncthreads();
    if (k0 + BK < K) loadT(k0 + BK);
#pragma unroll
    for (int kk = 0; kk < 2; ++kk) {
      bf16x8 af[4], bfr[4];
#pragma unroll
      for (int i = 0; i < 4; ++i) af[i] = *(const bf16x8*)&As[wm * 64 + i * 16 + r][kk * 32 + kg];
#pragma unroll
      for (int j = 0; j < 4; ++j) bfr[j] = *(const bf16x8*)&Bs[wn * 64 + j * 16 + r][kk * 32 + kg];
#pragma unroll
      for (int i = 0; i < 4; ++i)
#pragma unroll
        for (int j = 0; j < 4; ++j)
          acc[i][j] = __builtin_amdgcn_mfma_f32_16x16x32_bf16(af[i], bfr[j], acc[i][j], 0, 0, 0);
    }
    __syncthreads();
  }

  const int q4 = (lane >> 4) * 4;
#pragma unroll
  for (int i = 0; i < 4; ++i) {
    int gmb = m0 + wm * 64 + i * 16 + q4;
#pragma unroll
    for (int j = 0; j < 4; ++j) {
      int gn = n0 + wn * 64 + j * 16 + r;
#pragma unroll
      for (int qq = 0; qq < 4; ++qq) {
        float v = acc[i][j][qq];
        int m = gmb + qq;
        if constexpr (EPI == 2) {
          float u = v + bias[gn];
          u = 0.5f * u * (1.0f + erff(u * 0.70710678118654752f));
          ((short*)Cp + zC * zo)[(long)m * ldc + gn] = f2bf(u);
        } else {  // EPI == 5
          atomicAdd(&((float*)Cp + zC * zo)[(long)m * ldc + gn], v);
        }
      }
    }
  }
}

// ---------------- reduce 4 partials ----------------
__global__ __launch_bounds__(256) void reduce4_k(const float* __restrict__ p,
                                                 float* __restrict__ out) {
  int i = (blockIdx.x * 256 + threadIdx.x) * 4;
  float4 a = *(const float4*)&p[i];
  float4 b = *(const float4*)&p[i + 262144];
  float4 c = *(const float4*)&p[i + 524288];
  float4 d = *(const float4*)&p[i + 786432];
  float4 o;
  o.x = a.x + b.x + c.x + d.x;
  o.y = a.y + b.y + c.y + d.y;
  o.z = a.z + b.z + c.z + d.z;
  o.w = a.w + b.w + c.w + d.w;
  *(float4*)&out[i] = o;
}

// ---------------- softmax over s (in place) ----------------
__global__ __launch_bounds__(256) void softmax_k(float* __restrict__ scores) {
  long row = blockIdx.x;
  float* p = scores + row * 1024;
  int tid = threadIdx.x;
  int wid = tid >> 6, lane = tid & 63;
  float v[4];
  float mx = -1e30f;
#pragma unroll
  for (int i = 0; i < 4; ++i) { v[i] = p[tid + i * 256]; mx = fmaxf(mx, v[i]); }
  for (int o = 32; o; o >>= 1) mx = fmaxf(mx, __shfl_xor(mx, o));
  __shared__ float sm[4];
  __shared__ float ss[4];
  if (!lane) sm[wid] = mx;
  __syncthreads();
  mx = fmaxf(fmaxf(sm[0], sm[1]), fmaxf(sm[2], sm[3]));
  float s = 0.f;
#pragma unroll
  for (int i = 0; i < 4; ++i) { v[i] = expf(v[i] - mx); s += v[i]; }
  for (int o = 32; o; o >>= 1) s += __shfl_xor(s, o);
  if (!lane) ss[wid] = s;
  __syncthreads();
  s = ss[0] + ss[1] + ss[2] + ss[3];
  float inv = 1.0f / s;
#pragma unroll
  for (int i = 0; i < 4; ++i) p[tid + i * 256] = v[i] * inv;
}

// ---------------- attn_weights[b][t][s] = mean_h attn ----------------
__global__ __launch_bounds__(256) void attnw_k(const float* __restrict__ attn,
                                               float* __restrict__ outw) {
  int idx = blockIdx.x * 256 + threadIdx.x;
  int b = idx >> 13;
  int r = idx & 8191;
  int t = r >> 10, s = r & 1023;
  const float* p = attn + (long)b * 131072 + (long)t * 1024 + s;
  float acc = 0.f;
#pragma unroll
  for (int h = 0; h < 16; ++h) acc += p[(long)h * 8192];
  outw[idx] = acc * (1.0f / 16.0f);
}

// ---------------- fused aop-reduce + layernorm + gate softmax + top2 ----------------
// Reads 4 K-split partials of attn_out, adds out_b, writes attn_out (w/ out_b folded).
__global__ __launch_bounds__(256) void ln_gate_k(const float* __restrict__ aop,
                                                 const float* __restrict__ out_b,
                                                 const float* __restrict__ gamma,
                                                 const float* __restrict__ beta,
                                                 const float* __restrict__ gate_w,
                                                 float* __restrict__ attn_out,
                                                 short* __restrict__ yb,
                                                 float* __restrict__ gates,
                                                 float* __restrict__ Psum,
                                                 float* __restrict__ fcnt) {
  int row = blockIdx.x;        // n = b*8 + t
  int t = row & 7;
  int tid = threadIdx.x;
  int wid = tid >> 6, lane = tid & 63;
  const float* xr = aop + (long)row * 1024;
  float vals[4];
  float s = 0.f, sq = 0.f;
#pragma unroll
  for (int i = 0; i < 4; ++i) {
    int d = tid + i * 256;
    float v = xr[d] + xr[d + 262144] + xr[d + 524288] + xr[d + 786432] + out_b[d];
    attn_out[(long)row * 1024 + d] = v;
    vals[i] = v;
    s += v;
    sq += v * v;
  }
  for (int o = 32; o; o >>= 1) { s += __shfl_xor(s, o); sq += __shfl_xor(sq, o); }
  __shared__ float rs[4], rss[4];
  if (!lane) { rs[wid] = s; rss[wid] = sq; }
  __syncthreads();
  s = rs[0] + rs[1] + rs[2] + rs[3];
  sq = rss[0] + rss[1] + rss[2] + rss[3];
  float mu = s * (1.0f / 1024.0f);
  float var = sq * (1.0f / 1024.0f) - mu * mu;
  float rstd = rsqrtf(var + 1e-5f);
  __shared__ float yrow[1024];
#pragma unroll
  for (int i = 0; i < 4; ++i) {
    int d = tid + i * 256;
    float yv = (vals[i] - mu) * rstd * gamma[d] + beta[d];
    yb[(long)row * 1024 + d] = f2bf(yv);
    yrow[d] = yv;
  }
  __syncthreads();
  int e = tid & 7;
  int g = tid >> 3;
  float acc = 0.f;
  const float* gw = gate_w + (long)t * 8192;
  for (int d = g; d < 1024; d += 32) acc += yrow[d] * gw[d * 8 + e];
  __shared__ float part[256];
  __shared__ float lsh[8];
  part[tid] = acc;
  __syncthreads();
  if (tid < 8) {
    float l = 0.f;
    for (int gg = 0; gg < 32; ++gg) l += part[gg * 8 + tid];
    lsh[tid] = l;
  }
  __syncthreads();
  if (tid == 0) {
    float p[8];
    float mx = -1e30f;
    for (int k = 0; k < 8; ++k) mx = fmaxf(mx, lsh[k]);
    float sum = 0.f;
    for (int k = 0; k < 8; ++k) { p[k] = expf(lsh[k] - mx); sum += p[k]; }
    float inv = 1.0f / sum;
    for (int k = 0; k < 8; ++k) p[k] *= inv;
    int i0 = 0;
    for (int k = 1; k < 8; ++k) if (p[k] > p[i0]) i0 = k;
    int i1 = -1;
    for (int k = 0; k < 8; ++k) if (k != i0 && (i1 < 0 || p[k] > p[i1])) i1 = k;
    float tot = p[i0] + p[i1];
    for (int k = 0; k < 8; ++k)
      gates[(long)row * 8 + k] = (k == i0) ? p[i0] / tot : (k == i1) ? p[i1] / tot : 0.f;
    for (int k = 0; k < 8; ++k) atomicAdd(&Psum[k], p[k]);
    atomicAdd(&fcnt[i0], 1.0f);
    atomicAdd(&fcnt[i1], 1.0f);
  }
}

// ---------------- final = attn_out(+out_b already) + sum_e g_e * (eo[e] + b2[e]) ----------------
__global__ __launch_bounds__(256) void combine_k(const float* __restrict__ attn_out,
                                                 const float* __restrict__ eo,
                                                 const float* __restrict__ b2,
                                                 const float* __restrict__ gates,
                                                 float* __restrict__ outp) {
  int idx = blockIdx.x * 256 + threadIdx.x;
  int n = idx >> 10, d = idx & 1023;
  float v = attn_out[idx];
  const float* g = gates + (long)n * 8;
#pragma unroll
  for (int e = 0; e < 8; ++e) {
    float ge = g[e];
    if (ge != 0.f) v += ge * (eo[(long)e * 262144 + idx] + b2[e * 1024 + d]);
  }
  outp[idx] = v;
}

__global__ void loss_k(const float* __restrict__ Psum, const float* __restrict__ fcnt,
                       float* __restrict__ out) {
  if (threadIdx.x == 0) {
    float l = 0.f;
    for (int e = 0; e < 8; ++e) l += (fcnt[e] * (1.0f / 256.0f)) * (Psum[e] * (1.0f / 256.0f));
    out[0] = 8.0f * l;
  }
}

extern "C" void kernel_launch(void* const* d_in, const int* in_sizes, int n_in,
                              void* d_out, int out_size, void* d_ws, size_t ws_size,
                              hipStream_t stream) {
  const float* x      = (const float*)d_in[0];
  const float* probe  = (const float*)d_in[1];
  const float* in_w   = (const float*)d_in[2];
  const float* in_b   = (const float*)d_in[3];
  const float* out_w  = (const float*)d_in[4];
  const float* out_b  = (const float*)d_in[5];
  const float* gamma  = (const float*)d_in[6];
  const float* beta   = (const float*)d_in[7];
  const float* gate_w = (const float*)d_in[8];
  const float* w1     = (const float*)d_in[9];
  const float* b1     = (const float*)d_in[10];
  const float* w2     = (const float*)d_in[11];
  const float* b2     = (const float*)d_in[12];

  float* ws = (float*)d_ws;
  float* q        = ws + OFF_Q;
  float* qw       = ws + OFF_QW;
  float* qb       = ws + OFF_QB;
  float* Psum     = ws + OFF_PSUM;
  float* fcnt     = ws + OFF_FCNT;
  float* gates    = ws + OFF_GATES;
  float* ctx      = ws + OFF_CTX;
  float* attn_out = ws + OFF_ATTNOUT;
  float* eo       = ws + OFF_EO;
  float* ctxp     = ws + OFF_CTXP;
  float* aop      = ws + OFF_AOP;
  float* scores   = ws + OFF_SCORES;
  float* ax       = ws + OFF_AX;
  float* xT       = ws + OFF_XT;
  short* w1T      = (short*)(ws + OFF_XT);              // aliases xT (used after ax GEMM)
  short* w2T      = (short*)(ws + OFF_XT + 16777216);
  short* yb       = (short*)(ws + OFF_YB);
  short* hb       = (short*)(ws + OFF_HB);

  float* out_final = (float*)d_out;
  float* out_loss  = out_final + 262144;
  float* out_attnw = out_loss + 1;

  hipMemsetAsync(ws + OFF_PSUM, 0, 16 * sizeof(float), stream);
  hipMemsetAsync(eo, 0, 2097152 * sizeof(float), stream);

  compute_q_k<<<2048, 256, 0, stream>>>(probe, in_w, in_b, q);
  compute_qw_k<<<dim3(4, 16, 1), 256, 0, stream>>>(q, in_w, in_b, qw, qb);

  // xT[b][d][s] fp32
  transpose_x_k<<<dim3(16, 16, 32), 256, 0, stream>>>(x, xT);

  // scores[b][ht][s] = x @ qw^T + qb   (M=32768, N=128, K=1024) split
  gemm_ss<2, 2, 1, false, 1><<<dim3(1, 256, 1), 256, 0, stream>>>(
      x, qw, qb, x /*unused*/, scores, 1024, 1024, 1024, 0, 0, 0, 0, 0, 1024);

  softmax_k<<<4096, 256, 0, stream>>>(scores);
  attnw_k<<<1024, 256, 0, stream>>>(scores, out_attnw);

  // ax[h][b][t][d] = attn[b] @ xT[b]^T  (per b: M=128, N=1024, K=1024) split
  gemm_ss<2, 2, 1, false, 4><<<dim3(8, 1, 32), 256, 0, stream>>>(
      scores, xT, qb /*unused*/, x /*unused*/, ax, 1024, 1024, 1024,
      131072L, 1048576L, 0L, 8192L, 0L, 1024);

  // weight transposes (xT dead now; w1T/w2T alias it)
  transpose_w_k<<<dim3(64, 16, 8), 256, 0, stream>>>(w1, w1T, 1024, 4096);
  transpose_w_k<<<dim3(16, 64, 8), 256, 0, stream>>>(w2, w2T, 4096, 1024);

  // ctx partials: per (h, kc): M=256, N=64, K=256 split -> ctxp[kc][n][h*64+:]
  gemm_ss<1, 1, 4, false, 0><<<dim3(1, 4, 64), 64, 0, stream>>>(
      ax, in_w + 2097152, qb /*unused*/, x /*unused*/, ctxp, 1024, 1024, 256,
      262144L, 65536L, 0L, 64L, 262144L, 1024);
  reduce4_k<<<256, 256, 0, stream>>>(ctxp, ctx);

  // attn_out partials: A = ctx + bv(kbias), B = out_w  (M=256, N=1024, K=256 x4) split
  gemm_ss<1, 1, 4, true, 0><<<dim3(16, 4, 4), 64, 0, stream>>>(
      ctx, out_w, qb /*unused*/, in_b + 2048, aop, 1024, 1024, 256,
      0L, 0L, 0L, 0L, 262144L, 1024);

  // fused reduce + layernorm + gate + top2 (writes attn_out with out_b folded)
  ln_gate_k<<<256, 256, 0, stream>>>(aop, out_b, gamma, beta, gate_w, attn_out,
                                     yb, gates, Psum, fcnt);

  // h[e] = gelu(yb @ w1T[e]^T + b1[e])  (M=256, N=4096, K=1024) bf16
  gemm_bb<2, 2, 1, 2><<<dim3(32, 2, 8), 256, 0, stream>>>(
      yb, w1T, b1, hb, 1024, 1024, 1024, 0L, 4194304L, 4096L, 1048576L, 4096);

  // eo[e] += hb @ w2T[e]^T  (M=256, N=1024, K=1024 x4 ksplit, atomic) bf16
  gemm_bb<2, 2, 4, 5><<<dim3(8, 2, 32), 256, 0, stream>>>(
      hb, w2T, b1 /*unused*/, eo, 4096, 4096, 1024, 1048576L, 4194304L, 0L, 262144L, 1024);

  combine_k<<<1024, 256, 0, stream>>>(attn_out, eo, b2, gates, out_final);
  loss_k<<<1, 64, 0, stream>>>(Psum, fcnt, out_loss);
}

// Round 6
// 406.762 us; speedup vs baseline: 7.2160x; 1.1850x over previous
//
#include <hip/hip_runtime.h>
#include <hip/hip_bf16.h>
#include <math.h>

// B=32, S=1024, D=1024, H=16, dh=64, T=8, E=8, HID=4096
// Outputs fp32 concat: final(262144), moe_loss(1), attn_weights(262144)

using bf16x8  = __attribute__((ext_vector_type(8))) short;
using f32x4   = __attribute__((ext_vector_type(4))) float;
using short4v = __attribute__((ext_vector_type(4))) short;

__device__ inline short f2bf(float f) {
  unsigned u = __builtin_bit_cast(unsigned, f);
  u = (u + 0x7fffu + ((u >> 16) & 1u)) >> 16;
  return (short)u;
}

// ---------------- workspace layout (float offsets) ----------------
static constexpr long OFF_Q       = 0;         // 8192
static constexpr long OFF_QW      = 8192;      // 131072
static constexpr long OFF_QB      = 139264;    // 128
static constexpr long OFF_PSUM    = 139392;    // 8
static constexpr long OFF_FCNT    = 139400;    // 8
static constexpr long OFF_GATES   = 139408;    // 2048
static constexpr long OFF_CTX     = 141456;    // 262144 fp32
static constexpr long OFF_ATTNOUT = 403600;    // 262144 fp32
static constexpr long OFF_EO      = 665744;    // 2097152 fp32 [e][n][d] (zeroed)
static constexpr long OFF_CTXP    = 2762896;   // 1048576 fp32 (4 partials)
static constexpr long OFF_AOP     = 3811472;   // 1048576 fp32 (4 partials)
static constexpr long OFF_SCORES  = 4860048;   // 8388608 fp32: 2 planes [kc][b][ht][s]
static constexpr long OFF_AX      = 13248656;  // 8388608 fp32: 2 planes [kc][h][b][t][d]
static constexpr long OFF_YB      = 21637264;  // 131072 f = 262144 bf16
static constexpr long OFF_HB      = 21768336;  // 4194304 f = 8388608 bf16 [e][n][hid]
// end 25962640 floats ~ 104 MB

// ---------------- q: one wave per output element ----------------
__global__ __launch_bounds__(256) void compute_q_k(const float* __restrict__ probe,
                                                   const float* __restrict__ in_w,
                                                   const float* __restrict__ in_b,
                                                   float* __restrict__ q) {
  int wid = threadIdx.x >> 6, lane = threadIdx.x & 63;
  int idx = blockIdx.x * 4 + wid;   // t*1024 + d
  int t = idx >> 10, d = idx & 1023;
  const float* pr = probe + (long)t * 1024;
  const float* wr = in_w + (long)d * 1024;
  float s = 0.f;
  for (int k = lane * 4; k < 1024; k += 256) {
    float4 a = *(const float4*)&pr[k];
    float4 b = *(const float4*)&wr[k];
    s += a.x * b.x + a.y * b.y + a.z * b.z + a.w * b.w;
  }
  for (int o = 32; o; o >>= 1) s += __shfl_xor(s, o);
  if (!lane) q[idx] = s + in_b[d];
}

// ---------------- qw[h*8+t][d]; qb[ht]  (coalesced wk rows, LDS-broadcast q) ----------------
__global__ __launch_bounds__(256) void compute_qw_k(const float* __restrict__ q,
                                                    const float* __restrict__ in_w,
                                                    const float* __restrict__ in_b,
                                                    float* __restrict__ qw,
                                                    float* __restrict__ qb) {
  const int h = blockIdx.y;
  const int tid = threadIdx.x;
  const int d = blockIdx.x * 256 + tid;
  __shared__ float qh[8][64];
  if (tid < 64) {
#pragma unroll
    for (int t = 0; t < 8; ++t) qh[t][tid] = q[t * 1024 + h * 64 + tid] * 0.125f;
  }
  __syncthreads();
  const float* wk = in_w + 1048576 + (long)h * 64 * 1024;
  float acc[8];
#pragma unroll
  for (int t = 0; t < 8; ++t) acc[t] = 0.f;
  for (int j = 0; j < 64; ++j) {
    float w = wk[(long)j * 1024 + d];
#pragma unroll
    for (int t = 0; t < 8; ++t) acc[t] += qh[t][j] * w;
  }
#pragma unroll
  for (int t = 0; t < 8; ++t) qw[(long)(h * 8 + t) * 1024 + d] = acc[t];
  if (blockIdx.x == 0 && tid < 8) {
    float s = 0.f;
    for (int j = 0; j < 64; ++j) s += qh[tid][j] * in_b[1024 + h * 64 + j];
    qb[h * 8 + tid] = s;
  }
}

// ---------------- split-bf16 MFMA GEMM (fp32-grade), reg-prefetch ----------------
// A: M x K fp32 (lda); optional A2S adds A[ofs+zA2] (partial-plane sum); AKB adds kbias[k].
// B: BTRANS ? K x N row-major (ldb = row stride) transpose-staged : N x K row-major.
// z -> (zo=z/KS, kc=z%KS): A += kc*K cols; B += kc*K (cols) or kc*K*ldb (rows); C += ZKC*kc.
// EPI: 0 plain fp32 C[m*ldc+n]; 1 scores float4 scatter [b][ht][s]; 4 ax scatter [h][bt][d]
template<int WM, int WN, int KS, bool AKB, bool BTRANS, bool A2S, int EPI>
__global__ __launch_bounds__(WM * WN * 64)
void gemm_ss(const float* __restrict__ Ap, const float* __restrict__ Bp,
             const float* __restrict__ kbias, float* __restrict__ Cp,
             int lda, int ldb, int K,
             long zA, long zA2, long zB, long zC, long ZKC, int ldc) {
  constexpr int BM = WM * 64, BN = WN * 64, BK = 32, NT = WM * WN * 64, PK = 40;
  constexpr int LA = BM * BK / (NT * 4), LB = BN * BK / (NT * 4);
  constexpr int F4 = BN / 4;
  const int z = blockIdx.z, zo = z / KS, kc = z % KS;
  const float* A = Ap + zA * zo + (long)kc * K;
  const float* B = BTRANS ? (Bp + zB * zo + (long)kc * K * ldb)
                          : (Bp + zB * zo + (long)kc * K);
  const float* kb = kbias + (long)kc * K;
  float* C = Cp + zC * zo + ZKC * kc;
  const int tid = threadIdx.x;
  const int m0 = blockIdx.y * BM, n0 = blockIdx.x * BN;
  __shared__ short Ah[BM][PK], Al[BM][PK], Bh[BN][PK], Bl[BN][PK];

  f32x4 acc[4][4];
#pragma unroll
  for (int i = 0; i < 4; ++i)
#pragma unroll
    for (int j = 0; j < 4; ++j)
#pragma unroll
      for (int qq = 0; qq < 4; ++qq) acc[i][j][qq] = 0.f;

  const int wid = tid >> 6, lane = tid & 63;
  const int wm = wid % WM, wn = wid / WM;
  const int r = lane & 15, kg = (lane >> 4) * 8;

  float4 ra[LA], rb[LB];

  auto loadT = [&](int k0) {
#pragma unroll
    for (int i = 0; i < LA; ++i) {
      int f = tid + i * NT;
      int m = f >> 3, k4 = (f & 7) * 4;
      long ofs = (long)(m0 + m) * lda + k0 + k4;
      ra[i] = *(const float4*)&A[ofs];
      if (A2S) {
        float4 v2 = *(const float4*)&A[ofs + zA2];
        ra[i].x += v2.x; ra[i].y += v2.y; ra[i].z += v2.z; ra[i].w += v2.w;
      }
      if (AKB) {
        float4 kv = *(const float4*)&kb[k0 + k4];
        ra[i].x += kv.x; ra[i].y += kv.y; ra[i].z += kv.z; ra[i].w += kv.w;
      }
    }
#pragma unroll
    for (int i = 0; i < LB; ++i) {
      int f = tid + i * NT;
      if (BTRANS) {
        int k = f / F4, n4 = (f % F4) * 4;
        rb[i] = *(const float4*)&B[(long)(k0 + k) * ldb + n0 + n4];
      } else {
        int n = f >> 3, k4 = (f & 7) * 4;
        rb[i] = *(const float4*)&B[(long)(n0 + n) * ldb + k0 + k4];
      }
    }
  };

  auto storeT = [&]() {
#pragma unroll
    for (int i = 0; i < LA; ++i) {
      int f = tid + i * NT;
      int m = f >> 3, k4 = (f & 7) * 4;
      short4v h, l;
      float vv[4] = {ra[i].x, ra[i].y, ra[i].z, ra[i].w};
#pragma unroll
      for (int j = 0; j < 4; ++j) {
        unsigned u = __builtin_bit_cast(unsigned, vv[j]);
        h[j] = (short)(u >> 16);
        l[j] = f2bf(vv[j] - __builtin_bit_cast(float, u & 0xFFFF0000u));
      }
      *(short4v*)&Ah[m][k4] = h;
      *(short4v*)&Al[m][k4] = l;
    }
#pragma unroll
    for (int i = 0; i < LB; ++i) {
      int f = tid + i * NT;
      float vv[4] = {rb[i].x, rb[i].y, rb[i].z, rb[i].w};
      if (BTRANS) {
        int k = f / F4, n4 = (f % F4) * 4;
#pragma unroll
        for (int j = 0; j < 4; ++j) {
          unsigned u = __builtin_bit_cast(unsigned, vv[j]);
          Bh[n4 + j][k] = (short)(u >> 16);
          Bl[n4 + j][k] = f2bf(vv[j] - __builtin_bit_cast(float, u & 0xFFFF0000u));
        }
      } else {
        int n = f >> 3, k4 = (f & 7) * 4;
        short4v h, l;
#pragma unroll
        for (int j = 0; j < 4; ++j) {
          unsigned u = __builtin_bit_cast(unsigned, vv[j]);
          h[j] = (short)(u >> 16);
          l[j] = f2bf(vv[j] - __builtin_bit_cast(float, u & 0xFFFF0000u));
        }
        *(short4v*)&Bh[n][k4] = h;
        *(short4v*)&Bl[n][k4] = l;
      }
    }
  };

  loadT(0);
  for (int k0 = 0; k0 < K; k0 += BK) {
    storeT();
    __syncthreads();
    if (k0 + BK < K) loadT(k0 + BK);
    bf16x8 ah[4], al[4], bh[4], bl[4];
#pragma unroll
    for (int i = 0; i < 4; ++i) {
      ah[i] = *(const bf16x8*)&Ah[wm * 64 + i * 16 + r][kg];
      al[i] = *(const bf16x8*)&Al[wm * 64 + i * 16 + r][kg];
    }
#pragma unroll
    for (int j = 0; j < 4; ++j) {
      bh[j] = *(const bf16x8*)&Bh[wn * 64 + j * 16 + r][kg];
      bl[j] = *(const bf16x8*)&Bl[wn * 64 + j * 16 + r][kg];
    }
#pragma unroll
    for (int i = 0; i < 4; ++i)
#pragma unroll
      for (int j = 0; j < 4; ++j) {
        acc[i][j] = __builtin_amdgcn_mfma_f32_16x16x32_bf16(ah[i], bh[j], acc[i][j], 0, 0, 0);
        acc[i][j] = __builtin_amdgcn_mfma_f32_16x16x32_bf16(ah[i], bl[j], acc[i][j], 0, 0, 0);
        acc[i][j] = __builtin_amdgcn_mfma_f32_16x16x32_bf16(al[i], bh[j], acc[i][j], 0, 0, 0);
      }
    __syncthreads();
  }

  const int q4 = (lane >> 4) * 4;
#pragma unroll
  for (int i = 0; i < 4; ++i) {
    int gmb = m0 + wm * 64 + i * 16 + q4;
#pragma unroll
    for (int j = 0; j < 4; ++j) {
      int gn = n0 + wn * 64 + j * 16 + r;
      if constexpr (EPI == 1) {
        // m = b*1024+s (4 consecutive s) ; write scores[b][ht=gn][s..s+3]
        float4 v;
        v.x = acc[i][j][0]; v.y = acc[i][j][1]; v.z = acc[i][j][2]; v.w = acc[i][j][3];
        *(float4*)&C[(long)(gmb >> 10) * 131072 + (long)gn * 1024 + (gmb & 1023)] = v;
      } else {
#pragma unroll
        for (int qq = 0; qq < 4; ++qq) {
          float v = acc[i][j][qq];
          int m = gmb + qq;
          if constexpr (EPI == 0) {
            C[(long)m * ldc + gn] = v;
          } else {  // EPI == 4: m = h*8+t ; write [h][b*t-row][d] (C has b,kc offsets)
            C[(long)(m >> 3) * 262144 + (long)(m & 7) * 1024 + gn] = v;
          }
        }
      }
    }
  }
}

// ---------------- MoE MFMA GEMM: A bf16 MxK, B fp32 KxN (transpose+convert staged) ----------------
// BM=WM*64 (covers full M -> B read once), BN=WN*64. 512 threads for WM=4,WN=2.
// EPI: 2 gelu->bf16 +bias[n]; 5 atomicAdd fp32 (no bias)
template<int WM, int WN, int KS, int EPI>
__global__ __launch_bounds__(WM * WN * 64)
void gemm_moe(const short* __restrict__ Ap, const float* __restrict__ Bp,
              const float* __restrict__ biasp, void* __restrict__ Cp,
              int lda, int ldb, int K, long zA, long zB, long zBias, long zC, int ldc) {
  constexpr int BM = WM * 64, BN = WN * 64, BK = 32, NT = WM * WN * 64, PK = 40;
  constexpr int LA = BM * BK / (NT * 8), LB = BN * BK / (NT * 4);
  constexpr int F4 = BN / 4;
  const int z = blockIdx.z, zo = z / KS, kc = z % KS;
  const short* A = Ap + zA * zo + (long)kc * K;
  const float* B = Bp + zB * zo + (long)kc * K * ldb;
  const float* bias = biasp + zBias * zo;
  const int tid = threadIdx.x;
  const int m0 = blockIdx.y * BM, n0 = blockIdx.x * BN;
  __shared__ short As[BM][PK], Bs[BN][PK];

  f32x4 acc[4][4];
#pragma unroll
  for (int i = 0; i < 4; ++i)
#pragma unroll
    for (int j = 0; j < 4; ++j)
#pragma unroll
      for (int qq = 0; qq < 4; ++qq) acc[i][j][qq] = 0.f;

  const int wid = tid >> 6, lane = tid & 63;
  const int wm = wid % WM, wn = wid / WM;
  const int r = lane & 15, kg = (lane >> 4) * 8;

  bf16x8 ra[LA];
  float4 rb[LB];

  auto loadT = [&](int k0) {
#pragma unroll
    for (int i = 0; i < LA; ++i) {
      int f = tid + i * NT;
      int m = f >> 2, k8 = (f & 3) * 8;
      ra[i] = *(const bf16x8*)&A[(long)(m0 + m) * lda + k0 + k8];
    }
#pragma unroll
    for (int i = 0; i < LB; ++i) {
      int f = tid + i * NT;
      int k = f / F4, n4 = (f % F4) * 4;
      rb[i] = *(const float4*)&B[(long)(k0 + k) * ldb + n0 + n4];
    }
  };

  loadT(0);
  for (int k0 = 0; k0 < K; k0 += BK) {
#pragma unroll
    for (int i = 0; i < LA; ++i) {
      int f = tid + i * NT;
      int m = f >> 2, k8 = (f & 3) * 8;
      *(bf16x8*)&As[m][k8] = ra[i];
    }
#pragma unroll
    for (int i = 0; i < LB; ++i) {
      int f = tid + i * NT;
      int k = f / F4, n4 = (f % F4) * 4;
      Bs[n4 + 0][k] = f2bf(rb[i].x);
      Bs[n4 + 1][k] = f2bf(rb[i].y);
      Bs[n4 + 2][k] = f2bf(rb[i].z);
      Bs[n4 + 3][k] = f2bf(rb[i].w);
    }
    __syncthreads();
    if (k0 + BK < K) loadT(k0 + BK);
    bf16x8 af[4], bfr[4];
#pragma unroll
    for (int i = 0; i < 4; ++i) af[i] = *(const bf16x8*)&As[wm * 64 + i * 16 + r][kg];
#pragma unroll
    for (int j = 0; j < 4; ++j) bfr[j] = *(const bf16x8*)&Bs[wn * 64 + j * 16 + r][kg];
#pragma unroll
    for (int i = 0; i < 4; ++i)
#pragma unroll
      for (int j = 0; j < 4; ++j)
        acc[i][j] = __builtin_amdgcn_mfma_f32_16x16x32_bf16(af[i], bfr[j], acc[i][j], 0, 0, 0);
    __syncthreads();
  }

  const int q4 = (lane >> 4) * 4;
#pragma unroll
  for (int i = 0; i < 4; ++i) {
    int gmb = m0 + wm * 64 + i * 16 + q4;
#pragma unroll
    for (int j = 0; j < 4; ++j) {
      int gn = n0 + wn * 64 + j * 16 + r;
#pragma unroll
      for (int qq = 0; qq < 4; ++qq) {
        float v = acc[i][j][qq];
        int m = gmb + qq;
        if constexpr (EPI == 2) {
          float u = v + bias[gn];
          u = 0.5f * u * (1.0f + erff(u * 0.70710678118654752f));
          ((short*)Cp + zC * zo)[(long)m * ldc + gn] = f2bf(u);
        } else {  // EPI == 5
          atomicAdd(&((float*)Cp + zC * zo)[(long)m * ldc + gn], v);
        }
      }
    }
  }
}

// ---------------- reduce 4 partials ----------------
__global__ __launch_bounds__(256) void reduce4_k(const float* __restrict__ p,
                                                 float* __restrict__ out) {
  int i = (blockIdx.x * 256 + threadIdx.x) * 4;
  float4 a = *(const float4*)&p[i];
  float4 b = *(const float4*)&p[i + 262144];
  float4 c = *(const float4*)&p[i + 524288];
  float4 d = *(const float4*)&p[i + 786432];
  float4 o;
  o.x = a.x + b.x + c.x + d.x;
  o.y = a.y + b.y + c.y + d.y;
  o.z = a.z + b.z + c.z + d.z;
  o.w = a.w + b.w + c.w + d.w;
  *(float4*)&out[i] = o;
}

// ---------------- softmax: sum 2 score planes + qb bias, normalize into plane 0 ----------------
__global__ __launch_bounds__(256) void softmax_k(float* __restrict__ scores,
                                                 const float* __restrict__ qb) {
  long row = blockIdx.x;            // b*128 + ht
  int ht = (int)(row & 127);
  float bias = qb[ht];
  float* p = scores + row * 1024;
  const float* p2 = p + 4194304;
  int tid = threadIdx.x;
  int wid = tid >> 6, lane = tid & 63;
  float v[4];
  float mx = -1e30f;
#pragma unroll
  for (int i = 0; i < 4; ++i) {
    int idx = tid + i * 256;
    v[i] = p[idx] + p2[idx] + bias;
    mx = fmaxf(mx, v[i]);
  }
  for (int o = 32; o; o >>= 1) mx = fmaxf(mx, __shfl_xor(mx, o));
  __shared__ float sm[4];
  __shared__ float ss[4];
  if (!lane) sm[wid] = mx;
  __syncthreads();
  mx = fmaxf(fmaxf(sm[0], sm[1]), fmaxf(sm[2], sm[3]));
  float s = 0.f;
#pragma unroll
  for (int i = 0; i < 4; ++i) { v[i] = expf(v[i] - mx); s += v[i]; }
  for (int o = 32; o; o >>= 1) s += __shfl_xor(s, o);
  if (!lane) ss[wid] = s;
  __syncthreads();
  s = ss[0] + ss[1] + ss[2] + ss[3];
  float inv = 1.0f / s;
#pragma unroll
  for (int i = 0; i < 4; ++i) p[tid + i * 256] = v[i] * inv;
}

// ---------------- attn_weights[b][t][s] = mean_h attn ----------------
__global__ __launch_bounds__(256) void attnw_k(const float* __restrict__ attn,
                                               float* __restrict__ outw) {
  int idx = blockIdx.x * 256 + threadIdx.x;
  int b = idx >> 13;
  int r = idx & 8191;
  int t = r >> 10, s = r & 1023;
  const float* p = attn + (long)b * 131072 + (long)t * 1024 + s;
  float acc = 0.f;
#pragma unroll
  for (int h = 0; h < 16; ++h) acc += p[(long)h * 8192];
  outw[idx] = acc * (1.0f / 16.0f);
}

// ---------------- fused aop-reduce + layernorm + gate softmax + top2 ----------------
__global__ __launch_bounds__(256) void ln_gate_k(const float* __restrict__ aop,
                                                 const float* __restrict__ out_b,
                                                 const float* __restrict__ gamma,
                                                 const float* __restrict__ beta,
                                                 const float* __restrict__ gate_w,
                                                 float* __restrict__ attn_out,
                                                 short* __restrict__ yb,
                                                 float* __restrict__ gates,
                                                 float* __restrict__ Psum,
                                                 float* __restrict__ fcnt) {
  int row = blockIdx.x;        // n = b*8 + t
  int t = row & 7;
  int tid = threadIdx.x;
  int wid = tid >> 6, lane = tid & 63;
  const float* xr = aop + (long)row * 1024;
  float vals[4];
  float s = 0.f, sq = 0.f;
#pragma unroll
  for (int i = 0; i < 4; ++i) {
    int d = tid + i * 256;
    float v = xr[d] + xr[d + 262144] + xr[d + 524288] + xr[d + 786432] + out_b[d];
    attn_out[(long)row * 1024 + d] = v;
    vals[i] = v;
    s += v;
    sq += v * v;
  }
  for (int o = 32; o; o >>= 1) { s += __shfl_xor(s, o); sq += __shfl_xor(sq, o); }
  __shared__ float rs[4], rss[4];
  if (!lane) { rs[wid] = s; rss[wid] = sq; }
  __syncthreads();
  s = rs[0] + rs[1] + rs[2] + rs[3];
  sq = rss[0] + rss[1] + rss[2] + rss[3];
  float mu = s * (1.0f / 1024.0f);
  float var = sq * (1.0f / 1024.0f) - mu * mu;
  float rstd = rsqrtf(var + 1e-5f);
  __shared__ float yrow[1024];
#pragma unroll
  for (int i = 0; i < 4; ++i) {
    int d = tid + i * 256;
    float yv = (vals[i] - mu) * rstd * gamma[d] + beta[d];
    yb[(long)row * 1024 + d] = f2bf(yv);
    yrow[d] = yv;
  }
  __syncthreads();
  int e = tid & 7;
  int g = tid >> 3;
  float acc = 0.f;
  const float* gw = gate_w + (long)t * 8192;
  for (int d = g; d < 1024; d += 32) acc += yrow[d] * gw[d * 8 + e];
  __shared__ float part[256];
  __shared__ float lsh[8];
  part[tid] = acc;
  __syncthreads();
  if (tid < 8) {
    float l = 0.f;
    for (int gg = 0; gg < 32; ++gg) l += part[gg * 8 + tid];
    lsh[tid] = l;
  }
  __syncthreads();
  if (tid == 0) {
    float p[8];
    float mx = -1e30f;
    for (int k = 0; k < 8; ++k) mx = fmaxf(mx, lsh[k]);
    float sum = 0.f;
    for (int k = 0; k < 8; ++k) { p[k] = expf(lsh[k] - mx); sum += p[k]; }
    float inv = 1.0f / sum;
    for (int k = 0; k < 8; ++k) p[k] *= inv;
    int i0 = 0;
    for (int k = 1; k < 8; ++k) if (p[k] > p[i0]) i0 = k;
    int i1 = -1;
    for (int k = 0; k < 8; ++k) if (k != i0 && (i1 < 0 || p[k] > p[i1])) i1 = k;
    float tot = p[i0] + p[i1];
    for (int k = 0; k < 8; ++k)
      gates[(long)row * 8 + k] = (k == i0) ? p[i0] / tot : (k == i1) ? p[i1] / tot : 0.f;
    for (int k = 0; k < 8; ++k) atomicAdd(&Psum[k], p[k]);
    atomicAdd(&fcnt[i0], 1.0f);
    atomicAdd(&fcnt[i1], 1.0f);
  }
}

// ---------------- final = attn_out(+out_b) + sum_e g_e * (eo[e] + b2[e]) ----------------
__global__ __launch_bounds__(256) void combine_k(const float* __restrict__ attn_out,
                                                 const float* __restrict__ eo,
                                                 const float* __restrict__ b2,
                                                 const float* __restrict__ gates,
                                                 float* __restrict__ outp) {
  int idx = blockIdx.x * 256 + threadIdx.x;
  int n = idx >> 10, d = idx & 1023;
  float v = attn_out[idx];
  const float* g = gates + (long)n * 8;
#pragma unroll
  for (int e = 0; e < 8; ++e) {
    float ge = g[e];
    if (ge != 0.f) v += ge * (eo[(long)e * 262144 + idx] + b2[e * 1024 + d]);
  }
  outp[idx] = v;
}

__global__ void loss_k(const float* __restrict__ Psum, const float* __restrict__ fcnt,
                       float* __restrict__ out) {
  if (threadIdx.x == 0) {
    float l = 0.f;
    for (int e = 0; e < 8; ++e) l += (fcnt[e] * (1.0f / 256.0f)) * (Psum[e] * (1.0f / 256.0f));
    out[0] = 8.0f * l;
  }
}

extern "C" void kernel_launch(void* const* d_in, const int* in_sizes, int n_in,
                              void* d_out, int out_size, void* d_ws, size_t ws_size,
                              hipStream_t stream) {
  const float* x      = (const float*)d_in[0];
  const float* probe  = (const float*)d_in[1];
  const float* in_w   = (const float*)d_in[2];
  const float* in_b   = (const float*)d_in[3];
  const float* out_w  = (const float*)d_in[4];
  const float* out_b  = (const float*)d_in[5];
  const float* gamma  = (const float*)d_in[6];
  const float* beta   = (const float*)d_in[7];
  const float* gate_w = (const float*)d_in[8];
  const float* w1     = (const float*)d_in[9];
  const float* b1     = (const float*)d_in[10];
  const float* w2     = (const float*)d_in[11];
  const float* b2     = (const float*)d_in[12];

  float* ws = (float*)d_ws;
  float* q        = ws + OFF_Q;
  float* qw       = ws + OFF_QW;
  float* qb       = ws + OFF_QB;
  float* Psum     = ws + OFF_PSUM;
  float* fcnt     = ws + OFF_FCNT;
  float* gates    = ws + OFF_GATES;
  float* ctx      = ws + OFF_CTX;
  float* attn_out = ws + OFF_ATTNOUT;
  float* eo       = ws + OFF_EO;
  float* ctxp     = ws + OFF_CTXP;
  float* aop      = ws + OFF_AOP;
  float* scores   = ws + OFF_SCORES;
  float* axp      = ws + OFF_AX;
  short* yb       = (short*)(ws + OFF_YB);
  short* hb       = (short*)(ws + OFF_HB);

  float* out_final = (float*)d_out;
  float* out_loss  = out_final + 262144;
  float* out_attnw = out_loss + 1;

  hipMemsetAsync(ws + OFF_PSUM, 0, 16 * sizeof(float), stream);
  hipMemsetAsync(eo, 0, 2097152 * sizeof(float), stream);

  compute_q_k<<<2048, 256, 0, stream>>>(probe, in_w, in_b, q);
  compute_qw_k<<<dim3(4, 16, 1), 256, 0, stream>>>(q, in_w, in_b, qw, qb);

  // scores partials: [kc][b][ht][s] = x(:, kc*512+:512) @ qw(:, kc*512+:512)^T
  // (M=32768, N=128, K=512 x2) split; bias applied in softmax
  gemm_ss<2, 2, 2, false, false, false, 1><<<dim3(1, 256, 2), 256, 0, stream>>>(
      x, qw, qb /*unused*/, scores, 1024, 1024, 512,
      0L, 0L, 0L, 0L, 4194304L, 1024);

  softmax_k<<<4096, 256, 0, stream>>>(scores, qb);
  attnw_k<<<1024, 256, 0, stream>>>(scores, out_attnw);

  // ax partials: [kc][h][b][t][d] = attn[b](:, kc*512+:) @ x[b](kc*512+:, :)
  // (per (b,kc): M=128, N=1024, K=512) split, B transpose-staged from row-major x
  gemm_ss<2, 2, 2, false, true, false, 4><<<dim3(8, 1, 64), 256, 0, stream>>>(
      scores, x, qb /*unused*/, axp, 1024, 1024, 512,
      131072L, 0L, 1048576L, 8192L, 4194304L, 1024);

  // ctx partials: per (h, kc): M=256, N=64, K=256 split; A = axp0 + axp1 (A2S)
  gemm_ss<1, 1, 4, false, false, true, 0><<<dim3(1, 4, 64), 64, 0, stream>>>(
      axp, in_w + 2097152, qb /*unused*/, ctxp, 1024, 1024, 256,
      262144L, 4194304L, 65536L, 64L, 262144L, 1024);
  reduce4_k<<<256, 256, 0, stream>>>(ctxp, ctx);

  // attn_out partials: A = ctx + bv(kbias), B = out_w  (M=256, N=1024, K=256 x4) split
  gemm_ss<1, 1, 4, true, false, false, 0><<<dim3(16, 4, 4), 64, 0, stream>>>(
      ctx, out_w, in_b + 2048, aop, 1024, 1024, 256,
      0L, 0L, 0L, 0L, 262144L, 1024);

  // fused reduce + layernorm + gate + top2 (writes attn_out with out_b folded)
  ln_gate_k<<<256, 256, 0, stream>>>(aop, out_b, gamma, beta, gate_w, attn_out,
                                     yb, gates, Psum, fcnt);

  // h[e] = gelu(yb @ w1[e] + b1[e])  (M=256, N=4096, K=1024), B = w1[e] fp32 KxN direct
  gemm_moe<4, 2, 1, 2><<<dim3(32, 1, 8), 512, 0, stream>>>(
      yb, w1, b1, hb, 1024, 4096, 1024, 0L, 4194304L, 4096L, 1048576L, 4096);

  // eo[e] += hb @ w2[e]  (M=256, N=1024, K=1024 x4 ksplit, atomic), B = w2[e] fp32 KxN
  gemm_moe<4, 2, 4, 5><<<dim3(8, 1, 32), 512, 0, stream>>>(
      hb, w2, b1 /*unused*/, eo, 4096, 1024, 1024, 1048576L, 4194304L, 0L, 262144L, 1024);

  combine_k<<<1024, 256, 0, stream>>>(attn_out, eo, b2, gates, out_final);
  loss_k<<<1, 64, 0, stream>>>(Psum, fcnt, out_loss);
}